// Round 1
// baseline (1749.375 us; speedup 1.0000x reference)
//
#include <hip/hip_runtime.h>
#include <math.h>

#define IN_DIM 128
#define HD 256
#define NHID 32
#define EPSLN 1e-5f

// ---------------- GEMM: C[M x Nc] = A[M x K] @ W[K x Nc] + bias ----------------
__global__ __launch_bounds__(256) void gemm_bias(
    const float* __restrict__ A, const float* __restrict__ W,
    const float* __restrict__ bias, float* __restrict__ C,
    int M, int K, int Nc)
{
    __shared__ float As[16][68];   // [BK][BM+pad] — pad 4 keeps 16B align, kills write conflicts
    __shared__ float Ws[16][64];   // [BK][BN]
    int tid = threadIdx.x;
    int tx = tid & 15, ty = tid >> 4;
    int row0 = blockIdx.x * 64, col0 = blockIdx.y * 64;
    float acc[4][4];
#pragma unroll
    for (int i = 0; i < 4; i++)
#pragma unroll
        for (int j = 0; j < 4; j++) acc[i][j] = 0.f;

    for (int k0 = 0; k0 < K; k0 += 16) {
#pragma unroll
        for (int t = 0; t < 4; t++) {
            int idx = tid + t * 256;
            int m = idx >> 4, c = idx & 15;
            int r = row0 + m;
            As[c][m] = (r < M) ? A[(size_t)r * K + k0 + c] : 0.f;
        }
#pragma unroll
        for (int t = 0; t < 4; t++) {
            int idx = tid + t * 256;
            int kk = idx >> 6, nn = idx & 63;
            Ws[kk][nn] = W[(size_t)(k0 + kk) * Nc + col0 + nn];
        }
        __syncthreads();
#pragma unroll
        for (int kk = 0; kk < 16; kk++) {
            float4 a4 = *(const float4*)&As[kk][ty << 2];
            float4 b4 = *(const float4*)&Ws[kk][tx << 2];
            float a[4] = {a4.x, a4.y, a4.z, a4.w};
            float b[4] = {b4.x, b4.y, b4.z, b4.w};
#pragma unroll
            for (int i = 0; i < 4; i++)
#pragma unroll
                for (int j = 0; j < 4; j++) acc[i][j] = fmaf(a[i], b[j], acc[i][j]);
        }
        __syncthreads();
    }
#pragma unroll
    for (int i = 0; i < 4; i++) {
        int r = row0 + (ty << 2) + i;
        if (r < M) {
            int cb = col0 + (tx << 2);
            float4 o;
            o.x = acc[i][0] + bias[cb + 0];
            o.y = acc[i][1] + bias[cb + 1];
            o.z = acc[i][2] + bias[cb + 2];
            o.w = acc[i][3] + bias[cb + 3];
            *(float4*)&C[(size_t)r * Nc + cb] = o;
        }
    }
}

// ---------------- edge bucketing (counting sort by dst) ----------------
__global__ void count_k(const int* __restrict__ dst, int* __restrict__ counts, int E)
{
    int e = blockIdx.x * 256 + threadIdx.x;
    if (e < E) atomicAdd(&counts[dst[e]], 1);
}

__global__ __launch_bounds__(1024) void scan_k(const int* __restrict__ counts,
                                               int* __restrict__ offs, int n)
{
    __shared__ int wsum[16];
    __shared__ int carry_s;
    int tid = threadIdx.x, lane = tid & 63, wid = tid >> 6;
    if (tid == 0) carry_s = 0;
    __syncthreads();
    for (int base = 0; base < n; base += 1024) {
        int i = base + tid;
        int orig = (i < n) ? counts[i] : 0;
        int v = orig;
#pragma unroll
        for (int d = 1; d < 64; d <<= 1) {
            int t = __shfl_up(v, (unsigned)d, 64);
            if (lane >= d) v += t;
        }
        if (lane == 63) wsum[wid] = v;
        __syncthreads();
        int wpre = 0;
        for (int w2 = 0; w2 < wid; w2++) wpre += wsum[w2];
        if (i < n) offs[i] = carry_s + wpre + v - orig;
        __syncthreads();
        if (tid == 0) {
            int tot = 0;
            for (int w2 = 0; w2 < 16; w2++) tot += wsum[w2];
            carry_s += tot;
        }
        __syncthreads();
    }
    if (tid == 0) offs[n] = carry_s;
}

__global__ void scatter_k(const int* __restrict__ src, const int* __restrict__ dst,
                          const float* __restrict__ attr, const int* __restrict__ offs,
                          int* __restrict__ cursor, int* __restrict__ ssrc,
                          float* __restrict__ sattr, int E)
{
    int e = blockIdx.x * 256 + threadIdx.x;
    if (e < E) {
        int d = dst[e];
        int p = offs[d] + atomicAdd(&cursor[d], 1);
        ssrc[p] = src[e];
        sattr[p] = attr[e];
    }
}

// ---------------- attention: one wave per dst node, online softmax ----------------
// lane owns channels [4*lane, 4*lane+4) of the 256-dim feature (head = lane>>3).
__global__ __launch_bounds__(256) void attn_k(
    const float4* __restrict__ q, const float4* __restrict__ k4,
    const float4* __restrict__ v4, const float* __restrict__ We,
    float* __restrict__ hwork, const int* __restrict__ ssrc,
    const float* __restrict__ sattr, const int* __restrict__ offs,
    double* __restrict__ stats, int n)
{
    int lane = threadIdx.x & 63;
    int wid = threadIdx.x >> 6;
    int node = blockIdx.x * 4 + wid;
    float lsum = 0.f, lsq = 0.f;
    if (node < n) {
        float4 we = ((const float4*)We)[lane];
        float4 qv = q[(size_t)node * 64 + lane];
        float4 acc = make_float4(0.f, 0.f, 0.f, 0.f);
        float m = -INFINITY, l = 0.f;
        int i0 = offs[node], i1 = offs[node + 1];
        for (int i = i0; i < i1; i++) {
            int s = ssrc[i];
            float at = sattr[i];
            float4 kv = k4[(size_t)s * 64 + lane];
            float p = qv.x * fmaf(at, we.x, kv.x)
                    + qv.y * fmaf(at, we.y, kv.y)
                    + qv.z * fmaf(at, we.z, kv.z)
                    + qv.w * fmaf(at, we.w, kv.w);
            p += __shfl_xor(p, 1);
            p += __shfl_xor(p, 2);
            p += __shfl_xor(p, 4);
            p *= 0.17677669529663687f;   // 1/sqrt(32)
            float mn = fmaxf(m, p);
            float corr = __expf(m - mn); // 0 on first edge (m=-inf)
            float wgt = __expf(p - mn);
            l = l * corr + wgt;
            float4 vv = v4[(size_t)s * 64 + lane];
            acc.x = fmaf(acc.x, corr, wgt * fmaf(at, we.x, vv.x));
            acc.y = fmaf(acc.y, corr, wgt * fmaf(at, we.y, vv.y));
            acc.z = fmaf(acc.z, corr, wgt * fmaf(at, we.z, vv.z));
            acc.w = fmaf(acc.w, corr, wgt * fmaf(at, we.w, vv.w));
            m = mn;
        }
        float inv = (l > 0.f) ? 1.f / l : 0.f;
        float4 sk = ((const float4*)hwork)[(size_t)node * 64 + lane];
        float4 o;
        o.x = fmaf(acc.x, inv, sk.x);
        o.y = fmaf(acc.y, inv, sk.y);
        o.z = fmaf(acc.z, inv, sk.z);
        o.w = fmaf(acc.w, inv, sk.w);
        ((float4*)hwork)[(size_t)node * 64 + lane] = o;
        lsum = o.x + o.y + o.z + o.w;
        lsq = o.x * o.x + o.y * o.y + o.z * o.z + o.w * o.w;
    }
#pragma unroll
    for (int d = 1; d < 64; d <<= 1) {
        lsum += __shfl_xor(lsum, d);
        lsq += __shfl_xor(lsq, d);
    }
    __shared__ float red[8];
    if (lane == 0) { red[wid] = lsum; red[4 + wid] = lsq; }
    __syncthreads();
    if (threadIdx.x == 0) {
        double s = (double)red[0] + (double)red[1] + (double)red[2] + (double)red[3];
        double sq = (double)red[4] + (double)red[5] + (double)red[6] + (double)red[7];
        atomicAdd(&stats[0], s);
        atomicAdd(&stats[1], sq);
    }
}

// ---------------- LayerNorm finalize + apply ----------------
__global__ void ln_fin(const double* __restrict__ stats, float* __restrict__ lnp,
                       int idx, double cnt)
{
    if (threadIdx.x == 0 && blockIdx.x == 0) {
        double mean = stats[2 * idx] / cnt;
        double var = stats[2 * idx + 1] / cnt - mean * mean;
        if (var < 0.0) var = 0.0;
        lnp[2 * idx] = (float)mean;
        lnp[2 * idx + 1] = (float)(1.0 / (sqrt(var) + (double)EPSLN));
    }
}

__global__ __launch_bounds__(256) void ln_apply(
    const float4* __restrict__ in, float4* __restrict__ out,
    const float4* __restrict__ w4, const float4* __restrict__ b4,
    const float* __restrict__ lnp, int idx, int total4)
{
    int i = blockIdx.x * 256 + threadIdx.x;
    if (i >= total4) return;
    float mean = lnp[2 * idx], inv = lnp[2 * idx + 1];
    int c = i & 63;
    float4 xv = in[i], w = w4[c], b = b4[c];
    float4 o;
    o.x = fmaf((xv.x - mean) * inv, w.x, b.x);
    o.y = fmaf((xv.y - mean) * inv, w.y, b.y);
    o.z = fmaf((xv.z - mean) * inv, w.z, b.z);
    o.w = fmaf((xv.w - mean) * inv, w.w, b.w);
    o.x = o.x > 0.f ? o.x : expm1f(o.x);
    o.y = o.y > 0.f ? o.y : expm1f(o.y);
    o.z = o.z > 0.f ? o.z : expm1f(o.z);
    o.w = o.w > 0.f ? o.w : expm1f(o.w);
    out[i] = o;
}

// ---------------- driver ----------------
extern "C" void kernel_launch(void* const* d_in, const int* in_sizes, int n_in,
                              void* d_out, int out_size, void* d_ws, size_t ws_size,
                              hipStream_t stream)
{
    const float* x      = (const float*)d_in[0];
    const int*   ei     = (const int*)d_in[1];
    const float* eattr  = (const float*)d_in[2];
    const float* Wq1 = (const float*)d_in[3];  const float* bq1 = (const float*)d_in[4];
    const float* Wk1 = (const float*)d_in[5];  const float* bk1 = (const float*)d_in[6];
    const float* Wv1 = (const float*)d_in[7];  const float* bv1 = (const float*)d_in[8];
    const float* We1 = (const float*)d_in[9];
    const float* Ws1 = (const float*)d_in[10]; const float* bs1 = (const float*)d_in[11];
    const float* lnw1 = (const float*)d_in[12]; const float* lnb1 = (const float*)d_in[13];
    const float* Wq2 = (const float*)d_in[14]; const float* bq2 = (const float*)d_in[15];
    const float* Wk2 = (const float*)d_in[16]; const float* bk2 = (const float*)d_in[17];
    const float* Wv2 = (const float*)d_in[18]; const float* bv2 = (const float*)d_in[19];
    const float* We2 = (const float*)d_in[20];
    const float* Ws2 = (const float*)d_in[21]; const float* bs2 = (const float*)d_in[22];
    const float* lnw2 = (const float*)d_in[23]; const float* lnb2 = (const float*)d_in[24];
    const float* Wo  = (const float*)d_in[25]; const float* bo  = (const float*)d_in[26];

    const int N = in_sizes[0] / IN_DIM;
    const int E = in_sizes[2];
    const int* esrc = ei;
    const int* edst = ei + E;

    char* ws = (char*)d_ws;
    size_t off = 0;
    auto alloc = [&](size_t bytes) -> char* {
        char* p = ws + off;
        off += (bytes + 255) / 256 * 256;
        return p;
    };
    int*    counts = (int*)alloc((size_t)N * 4);
    int*    cursor = (int*)alloc((size_t)N * 4);
    double* stats  = (double*)alloc(64);     // [0,1]=layer1 sum/sumsq, [2,3]=layer2
    float*  lnp    = (float*)alloc(256);     // mean/inv per layer
    size_t zbytes = off;                     // everything above gets zeroed
    int*    offs   = (int*)alloc((size_t)(N + 1) * 4);
    int*    ssrc   = (int*)alloc((size_t)E * 4);
    float*  sattr  = (float*)alloc((size_t)E * 4);
    float*  qb     = (float*)alloc((size_t)N * HD * 4);
    float*  kb     = (float*)alloc((size_t)N * HD * 4);
    float*  vb     = (float*)alloc((size_t)N * HD * 4);
    float*  hwork  = (float*)alloc((size_t)N * HD * 4);  // skip in, attn out, LN in
    float*  hio    = (float*)alloc((size_t)N * HD * 4);  // LN out / next-layer input

    hipMemsetAsync(d_ws, 0, zbytes, stream);

    // edge bucketing by destination
    count_k<<<(E + 255) / 256, 256, 0, stream>>>(edst, counts, E);
    scan_k<<<1, 1024, 0, stream>>>(counts, offs, N);
    scatter_k<<<(E + 255) / 256, 256, 0, stream>>>(esrc, edst, eattr, offs, cursor,
                                                   ssrc, sattr, E);

    dim3 gg((N + 63) / 64, HD / 64);
    dim3 ga((N + 3) / 4);
    int total4 = N * (HD / 4);
    dim3 gl((total4 + 255) / 256);

    // ---- layer 1 ----
    gemm_bias<<<gg, 256, 0, stream>>>(x, Wq1, bq1, qb, N, IN_DIM, HD);
    gemm_bias<<<gg, 256, 0, stream>>>(x, Wk1, bk1, kb, N, IN_DIM, HD);
    gemm_bias<<<gg, 256, 0, stream>>>(x, Wv1, bv1, vb, N, IN_DIM, HD);
    gemm_bias<<<gg, 256, 0, stream>>>(x, Ws1, bs1, hwork, N, IN_DIM, HD);
    attn_k<<<ga, 256, 0, stream>>>((const float4*)qb, (const float4*)kb,
                                   (const float4*)vb, We1, hwork, ssrc, sattr,
                                   offs, stats, N);
    ln_fin<<<1, 64, 0, stream>>>(stats, lnp, 0, (double)N * HD);
    ln_apply<<<gl, 256, 0, stream>>>((const float4*)hwork, (float4*)hio,
                                     (const float4*)lnw1, (const float4*)lnb1,
                                     lnp, 0, total4);

    // ---- layer 2 ----
    gemm_bias<<<gg, 256, 0, stream>>>(hio, Wq2, bq2, qb, N, HD, HD);
    gemm_bias<<<gg, 256, 0, stream>>>(hio, Wk2, bk2, kb, N, HD, HD);
    gemm_bias<<<gg, 256, 0, stream>>>(hio, Wv2, bv2, vb, N, HD, HD);
    gemm_bias<<<gg, 256, 0, stream>>>(hio, Ws2, bs2, hwork, N, HD, HD);
    attn_k<<<ga, 256, 0, stream>>>((const float4*)qb, (const float4*)kb,
                                   (const float4*)vb, We2, hwork, ssrc, sattr,
                                   offs, stats + 2, N);
    ln_fin<<<1, 64, 0, stream>>>(stats, lnp, 1, (double)N * HD);
    ln_apply<<<gl, 256, 0, stream>>>((const float4*)hwork, (float4*)hio,
                                     (const float4*)lnw2, (const float4*)lnb2,
                                     lnp, 1, total4);

    // ---- output projection ----
    dim3 go((N + 63) / 64, 1);
    gemm_bias<<<go, 256, 0, stream>>>(hio, Wo, bo, (float*)d_out, N, HD, 64);
}

// Round 2
// 1627.764 us; speedup vs baseline: 1.0747x; 1.0747x over previous
//
#include <hip/hip_runtime.h>
#include <hip/hip_fp16.h>
#include <math.h>

#define IN_DIM 128
#define HD 256
#define NHID 32
#define EPSLN 1e-5f

// ---------------- store helpers (fp32 or fp16 output) ----------------
__device__ inline void store4(float* p, float4 o) { *(float4*)p = o; }
__device__ inline void store4(__half* p, float4 o) {
    union { uint2 u; __half2 h[2]; } s;
    s.h[0] = __floats2half2_rn(o.x, o.y);
    s.h[1] = __floats2half2_rn(o.z, o.w);
    *(uint2*)p = s.u;
}

__device__ inline float4 h4_to_f4(uint2 u) {
    union { unsigned int w; __half2 h; } a, b;
    a.w = u.x; b.w = u.y;
    float2 lo = __half22float2(a.h), hi = __half22float2(b.h);
    return make_float4(lo.x, lo.y, hi.x, hi.y);
}

// ---------------- GEMM: C[M x Nc] = A[M x K] @ W[K x Nc] + bias ----------------
template <typename OT>
__global__ __launch_bounds__(256) void gemm_bias(
    const float* __restrict__ A, const float* __restrict__ W,
    const float* __restrict__ bias, OT* __restrict__ C,
    int M, int K, int Nc)
{
    __shared__ float As[16][68];
    __shared__ float Ws[16][64];
    int tid = threadIdx.x;
    int tx = tid & 15, ty = tid >> 4;
    int row0 = blockIdx.x * 64, col0 = blockIdx.y * 64;
    float acc[4][4];
#pragma unroll
    for (int i = 0; i < 4; i++)
#pragma unroll
        for (int j = 0; j < 4; j++) acc[i][j] = 0.f;

    for (int k0 = 0; k0 < K; k0 += 16) {
#pragma unroll
        for (int t = 0; t < 4; t++) {
            int idx = tid + t * 256;
            int m = idx >> 4, c = idx & 15;
            int r = row0 + m;
            As[c][m] = (r < M) ? A[(size_t)r * K + k0 + c] : 0.f;
        }
#pragma unroll
        for (int t = 0; t < 4; t++) {
            int idx = tid + t * 256;
            int kk = idx >> 6, nn = idx & 63;
            Ws[kk][nn] = W[(size_t)(k0 + kk) * Nc + col0 + nn];
        }
        __syncthreads();
#pragma unroll
        for (int kk = 0; kk < 16; kk++) {
            float4 a4 = *(const float4*)&As[kk][ty << 2];
            float4 b4 = *(const float4*)&Ws[kk][tx << 2];
            float a[4] = {a4.x, a4.y, a4.z, a4.w};
            float b[4] = {b4.x, b4.y, b4.z, b4.w};
#pragma unroll
            for (int i = 0; i < 4; i++)
#pragma unroll
                for (int j = 0; j < 4; j++) acc[i][j] = fmaf(a[i], b[j], acc[i][j]);
        }
        __syncthreads();
    }
#pragma unroll
    for (int i = 0; i < 4; i++) {
        int r = row0 + (ty << 2) + i;
        if (r < M) {
            int cb = col0 + (tx << 2);
            float4 o;
            o.x = acc[i][0] + bias[cb + 0];
            o.y = acc[i][1] + bias[cb + 1];
            o.z = acc[i][2] + bias[cb + 2];
            o.w = acc[i][3] + bias[cb + 3];
            store4(&C[(size_t)r * Nc + cb], o);
        }
    }
}

// ---------------- edge bucketing (counting sort by dst) ----------------
__global__ void count_k(const int* __restrict__ dst, int* __restrict__ counts, int E)
{
    int e = blockIdx.x * 256 + threadIdx.x;
    if (e < E) atomicAdd(&counts[dst[e]], 1);
}

__global__ __launch_bounds__(1024) void scan_k(const int* __restrict__ counts,
                                               int* __restrict__ offs, int n)
{
    __shared__ int wsum[16];
    __shared__ int carry_s;
    int tid = threadIdx.x, lane = tid & 63, wid = tid >> 6;
    if (tid == 0) carry_s = 0;
    __syncthreads();
    for (int base = 0; base < n; base += 1024) {
        int i = base + tid;
        int orig = (i < n) ? counts[i] : 0;
        int v = orig;
#pragma unroll
        for (int d = 1; d < 64; d <<= 1) {
            int t = __shfl_up(v, (unsigned)d, 64);
            if (lane >= d) v += t;
        }
        if (lane == 63) wsum[wid] = v;
        __syncthreads();
        int wpre = 0;
        for (int w2 = 0; w2 < wid; w2++) wpre += wsum[w2];
        if (i < n) offs[i] = carry_s + wpre + v - orig;
        __syncthreads();
        if (tid == 0) {
            int tot = 0;
            for (int w2 = 0; w2 < 16; w2++) tot += wsum[w2];
            carry_s += tot;
        }
        __syncthreads();
    }
    if (tid == 0) offs[n] = carry_s;
}

__global__ void scatter_k(const int* __restrict__ src, const int* __restrict__ dst,
                          const float* __restrict__ attr, const int* __restrict__ offs,
                          int* __restrict__ cursor, int* __restrict__ ssrc,
                          float* __restrict__ sattr, int E)
{
    int e = blockIdx.x * 256 + threadIdx.x;
    if (e < E) {
        int d = dst[e];
        int p = offs[d] + atomicAdd(&cursor[d], 1);
        ssrc[p] = src[e];
        sattr[p] = attr[e];
    }
}

// ---------------- attention: one wave per dst node, online softmax ----------------
// lane owns channels [4*lane, 4*lane+4); q/k/v are fp16 (uint2 = 4 halves per lane).
__global__ __launch_bounds__(256) void attn_k(
    const uint2* __restrict__ qh, const uint2* __restrict__ kh,
    const uint2* __restrict__ vh, const float* __restrict__ We,
    float* __restrict__ hwork, const int* __restrict__ ssrc,
    const float* __restrict__ sattr, const int* __restrict__ offs,
    double* __restrict__ stats, int n)
{
    int lane = threadIdx.x & 63;
    int wid = threadIdx.x >> 6;
    int node = blockIdx.x * 4 + wid;
    float lsum = 0.f, lsq = 0.f;
    if (node < n) {
        float4 we = ((const float4*)We)[lane];
        float4 qv = h4_to_f4(qh[(size_t)node * 64 + lane]);
        float4 acc = make_float4(0.f, 0.f, 0.f, 0.f);
        float m = -INFINITY, l = 0.f;
        int i0 = offs[node], i1 = offs[node + 1];

        auto process = [&](uint2 kraw, uint2 vraw, float at) {
            float4 kv = h4_to_f4(kraw);
            float p = qv.x * fmaf(at, we.x, kv.x)
                    + qv.y * fmaf(at, we.y, kv.y)
                    + qv.z * fmaf(at, we.z, kv.z)
                    + qv.w * fmaf(at, we.w, kv.w);
            p += __shfl_xor(p, 1);
            p += __shfl_xor(p, 2);
            p += __shfl_xor(p, 4);
            p *= 0.17677669529663687f;   // 1/sqrt(32)
            float mn = fmaxf(m, p);
            float corr = __expf(m - mn);
            float wgt = __expf(p - mn);
            l = l * corr + wgt;
            float4 vv = h4_to_f4(vraw);
            acc.x = fmaf(acc.x, corr, wgt * fmaf(at, we.x, vv.x));
            acc.y = fmaf(acc.y, corr, wgt * fmaf(at, we.y, vv.y));
            acc.z = fmaf(acc.z, corr, wgt * fmaf(at, we.z, vv.z));
            acc.w = fmaf(acc.w, corr, wgt * fmaf(at, we.w, vv.w));
            m = mn;
        };

        int i = i0;
        // unroll x4: issue all 8 gathers before consuming any (MLP)
        for (; i + 4 <= i1; i += 4) {
            int s0 = ssrc[i], s1 = ssrc[i + 1], s2 = ssrc[i + 2], s3 = ssrc[i + 3];
            float t0 = sattr[i], t1 = sattr[i + 1], t2 = sattr[i + 2], t3 = sattr[i + 3];
            uint2 k0 = kh[(size_t)s0 * 64 + lane];
            uint2 k1 = kh[(size_t)s1 * 64 + lane];
            uint2 k2 = kh[(size_t)s2 * 64 + lane];
            uint2 k3 = kh[(size_t)s3 * 64 + lane];
            uint2 v0 = vh[(size_t)s0 * 64 + lane];
            uint2 v1 = vh[(size_t)s1 * 64 + lane];
            uint2 v2 = vh[(size_t)s2 * 64 + lane];
            uint2 v3 = vh[(size_t)s3 * 64 + lane];
            process(k0, v0, t0);
            process(k1, v1, t1);
            process(k2, v2, t2);
            process(k3, v3, t3);
        }
        for (; i < i1; i++) {
            int s = ssrc[i];
            float at = sattr[i];
            uint2 kraw = kh[(size_t)s * 64 + lane];
            uint2 vraw = vh[(size_t)s * 64 + lane];
            process(kraw, vraw, at);
        }

        float inv = (l > 0.f) ? 1.f / l : 0.f;
        float4 sk = ((const float4*)hwork)[(size_t)node * 64 + lane];
        float4 o;
        o.x = fmaf(acc.x, inv, sk.x);
        o.y = fmaf(acc.y, inv, sk.y);
        o.z = fmaf(acc.z, inv, sk.z);
        o.w = fmaf(acc.w, inv, sk.w);
        ((float4*)hwork)[(size_t)node * 64 + lane] = o;
        lsum = o.x + o.y + o.z + o.w;
        lsq = o.x * o.x + o.y * o.y + o.z * o.z + o.w * o.w;
    }
#pragma unroll
    for (int d = 1; d < 64; d <<= 1) {
        lsum += __shfl_xor(lsum, d);
        lsq += __shfl_xor(lsq, d);
    }
    __shared__ float red[8];
    if (lane == 0) { red[wid] = lsum; red[4 + wid] = lsq; }
    __syncthreads();
    if (threadIdx.x == 0) {
        double s = (double)red[0] + (double)red[1] + (double)red[2] + (double)red[3];
        double sq = (double)red[4] + (double)red[5] + (double)red[6] + (double)red[7];
        atomicAdd(&stats[0], s);
        atomicAdd(&stats[1], sq);
    }
}

// ---------------- LayerNorm finalize + apply ----------------
__global__ void ln_fin(const double* __restrict__ stats, float* __restrict__ lnp,
                       int idx, double cnt)
{
    if (threadIdx.x == 0 && blockIdx.x == 0) {
        double mean = stats[2 * idx] / cnt;
        double var = stats[2 * idx + 1] / cnt - mean * mean;
        if (var < 0.0) var = 0.0;
        lnp[2 * idx] = (float)mean;
        lnp[2 * idx + 1] = (float)(1.0 / (sqrt(var) + (double)EPSLN));
    }
}

__global__ __launch_bounds__(256) void ln_apply(
    const float4* __restrict__ in, float4* __restrict__ out,
    const float4* __restrict__ w4, const float4* __restrict__ b4,
    const float* __restrict__ lnp, int idx, int total4)
{
    int i = blockIdx.x * 256 + threadIdx.x;
    if (i >= total4) return;
    float mean = lnp[2 * idx], inv = lnp[2 * idx + 1];
    int c = i & 63;
    float4 xv = in[i], w = w4[c], b = b4[c];
    float4 o;
    o.x = fmaf((xv.x - mean) * inv, w.x, b.x);
    o.y = fmaf((xv.y - mean) * inv, w.y, b.y);
    o.z = fmaf((xv.z - mean) * inv, w.z, b.z);
    o.w = fmaf((xv.w - mean) * inv, w.w, b.w);
    o.x = o.x > 0.f ? o.x : expm1f(o.x);
    o.y = o.y > 0.f ? o.y : expm1f(o.y);
    o.z = o.z > 0.f ? o.z : expm1f(o.z);
    o.w = o.w > 0.f ? o.w : expm1f(o.w);
    out[i] = o;
}

// ---------------- driver ----------------
extern "C" void kernel_launch(void* const* d_in, const int* in_sizes, int n_in,
                              void* d_out, int out_size, void* d_ws, size_t ws_size,
                              hipStream_t stream)
{
    const float* x      = (const float*)d_in[0];
    const int*   ei     = (const int*)d_in[1];
    const float* eattr  = (const float*)d_in[2];
    const float* Wq1 = (const float*)d_in[3];  const float* bq1 = (const float*)d_in[4];
    const float* Wk1 = (const float*)d_in[5];  const float* bk1 = (const float*)d_in[6];
    const float* Wv1 = (const float*)d_in[7];  const float* bv1 = (const float*)d_in[8];
    const float* We1 = (const float*)d_in[9];
    const float* Ws1 = (const float*)d_in[10]; const float* bs1 = (const float*)d_in[11];
    const float* lnw1 = (const float*)d_in[12]; const float* lnb1 = (const float*)d_in[13];
    const float* Wq2 = (const float*)d_in[14]; const float* bq2 = (const float*)d_in[15];
    const float* Wk2 = (const float*)d_in[16]; const float* bk2 = (const float*)d_in[17];
    const float* Wv2 = (const float*)d_in[18]; const float* bv2 = (const float*)d_in[19];
    const float* We2 = (const float*)d_in[20];
    const float* Ws2 = (const float*)d_in[21]; const float* bs2 = (const float*)d_in[22];
    const float* lnw2 = (const float*)d_in[23]; const float* lnb2 = (const float*)d_in[24];
    const float* Wo  = (const float*)d_in[25]; const float* bo  = (const float*)d_in[26];

    const int N = in_sizes[0] / IN_DIM;
    const int E = in_sizes[2];
    const int* esrc = ei;
    const int* edst = ei + E;

    char* ws = (char*)d_ws;
    size_t off = 0;
    auto alloc = [&](size_t bytes) -> char* {
        char* p = ws + off;
        off += (bytes + 255) / 256 * 256;
        return p;
    };
    int*    counts = (int*)alloc((size_t)N * 4);
    int*    cursor = (int*)alloc((size_t)N * 4);
    double* stats  = (double*)alloc(64);
    float*  lnp    = (float*)alloc(256);
    size_t zbytes = off;
    int*    offs   = (int*)alloc((size_t)(N + 1) * 4);
    int*    ssrc   = (int*)alloc((size_t)E * 4);
    float*  sattr  = (float*)alloc((size_t)E * 4);
    __half* qb     = (__half*)alloc((size_t)N * HD * 2);
    __half* kb     = (__half*)alloc((size_t)N * HD * 2);
    __half* vb     = (__half*)alloc((size_t)N * HD * 2);
    float*  hwork  = (float*)alloc((size_t)N * HD * 4);
    float*  hio    = (float*)alloc((size_t)N * HD * 4);

    hipMemsetAsync(d_ws, 0, zbytes, stream);

    count_k<<<(E + 255) / 256, 256, 0, stream>>>(edst, counts, E);
    scan_k<<<1, 1024, 0, stream>>>(counts, offs, N);
    scatter_k<<<(E + 255) / 256, 256, 0, stream>>>(esrc, edst, eattr, offs, cursor,
                                                   ssrc, sattr, E);

    dim3 gg((N + 63) / 64, HD / 64);
    dim3 ga((N + 3) / 4);
    int total4 = N * (HD / 4);
    dim3 gl((total4 + 255) / 256);

    // ---- layer 1 ----
    gemm_bias<<<gg, 256, 0, stream>>>(x, Wq1, bq1, qb, N, IN_DIM, HD);
    gemm_bias<<<gg, 256, 0, stream>>>(x, Wk1, bk1, kb, N, IN_DIM, HD);
    gemm_bias<<<gg, 256, 0, stream>>>(x, Wv1, bv1, vb, N, IN_DIM, HD);
    gemm_bias<<<gg, 256, 0, stream>>>(x, Ws1, bs1, hwork, N, IN_DIM, HD);
    attn_k<<<ga, 256, 0, stream>>>((const uint2*)qb, (const uint2*)kb,
                                   (const uint2*)vb, We1, hwork, ssrc, sattr,
                                   offs, stats, N);
    ln_fin<<<1, 64, 0, stream>>>(stats, lnp, 0, (double)N * HD);
    ln_apply<<<gl, 256, 0, stream>>>((const float4*)hwork, (float4*)hio,
                                     (const float4*)lnw1, (const float4*)lnb1,
                                     lnp, 0, total4);

    // ---- layer 2 ----
    gemm_bias<<<gg, 256, 0, stream>>>(hio, Wq2, bq2, qb, N, HD, HD);
    gemm_bias<<<gg, 256, 0, stream>>>(hio, Wk2, bk2, kb, N, HD, HD);
    gemm_bias<<<gg, 256, 0, stream>>>(hio, Wv2, bv2, vb, N, HD, HD);
    gemm_bias<<<gg, 256, 0, stream>>>(hio, Ws2, bs2, hwork, N, HD, HD);
    attn_k<<<ga, 256, 0, stream>>>((const uint2*)qb, (const uint2*)kb,
                                   (const uint2*)vb, We2, hwork, ssrc, sattr,
                                   offs, stats + 2, N);
    ln_fin<<<1, 64, 0, stream>>>(stats, lnp, 1, (double)N * HD);
    ln_apply<<<gl, 256, 0, stream>>>((const float4*)hwork, (float4*)hio,
                                     (const float4*)lnw2, (const float4*)lnb2,
                                     lnp, 1, total4);

    // ---- output projection ----
    dim3 go((N + 63) / 64, 1);
    gemm_bias<<<go, 256, 0, stream>>>(hio, Wo, bo, (float*)d_out, N, HD, 64);
}

// Round 4
// 1150.082 us; speedup vs baseline: 1.5211x; 1.4153x over previous
//
#include <hip/hip_runtime.h>
#include <hip/hip_fp16.h>
#include <math.h>

#define IN_DIM 128
#define HD 256
#define EPSLN 1e-5f

typedef _Float16 half8 __attribute__((ext_vector_type(8)));
typedef float f32x4 __attribute__((ext_vector_type(4)));

// ---------------- helpers ----------------
__device__ inline void store4(float* p, float4 o) { *(float4*)p = o; }
__device__ inline void store4(__half* p, float4 o) {
    union { uint2 u; __half2 h[2]; } s;
    s.h[0] = __floats2half2_rn(o.x, o.y);
    s.h[1] = __floats2half2_rn(o.z, o.w);
    *(uint2*)p = s.u;
}
__device__ inline float4 h4_to_f4(uint2 u) {
    union { unsigned int w; __half2 h; } a, b;
    a.w = u.x; b.w = u.y;
    float2 lo = __half22float2(a.h), hi = __half22float2(b.h);
    return make_float4(lo.x, lo.y, hi.x, hi.y);
}
__device__ inline void storeC(__half* p, float v) { *p = __float2half(v); }
__device__ inline void storeC(float* p, float v) { *p = v; }

// ---------------- pack kernels (tiny, run every call) ----------------
__global__ void pack_x_k(const float4* __restrict__ x, __half* __restrict__ xh, int total4)
{
    int i = blockIdx.x * 256 + threadIdx.x;
    if (i < total4) store4(xh + (size_t)i * 4, x[i]);
}

// Wt[1024][K] f16, Wt[n][k] = Wsel[k][n&255]
__global__ void pack_wcat_k(const float* __restrict__ Wq, const float* __restrict__ Wk,
                            const float* __restrict__ Wv, const float* __restrict__ Ws,
                            __half* __restrict__ Wt, int K)
{
    int idx = blockIdx.x * 256 + threadIdx.x;
    if (idx >= 1024 * K) return;
    int n = idx / K, k = idx % K;
    int sel = n >> 8, c = n & 255;
    const float* W = (sel == 0) ? Wq : (sel == 1) ? Wk : (sel == 2) ? Wv : Ws;
    Wt[idx] = __float2half(W[(size_t)k * 256 + c]);
}

__global__ void pack_bcat_k(const float* __restrict__ bq, const float* __restrict__ bk,
                            const float* __restrict__ bv, const float* __restrict__ bs,
                            float* __restrict__ bcat)
{
    int n = blockIdx.x * 256 + threadIdx.x;
    if (n >= 1024) return;
    int sel = n >> 8, c = n & 255;
    const float* b = (sel == 0) ? bq : (sel == 1) ? bk : (sel == 2) ? bv : bs;
    bcat[n] = b[c];
}

// Wo_t[64][256] from Wo[256][64]
__global__ void pack_wo_k(const float* __restrict__ Wo, __half* __restrict__ Wot)
{
    int idx = blockIdx.x * 256 + threadIdx.x;
    if (idx >= 64 * 256) return;
    int n = idx >> 8, k = idx & 255;
    Wot[idx] = __float2half(Wo[(size_t)k * 64 + n]);
}

// ---------------- MFMA GEMM: C[M x Nc] = A[M x K] @ Wt^T + bias ----------------
// A [M][K] f16 row-major; Wt [Nc][K] f16 row-major (i.e. B transposed).
// Tile 128x128xBK32; 4 waves, each 64x64 via 4x4 mfma_f32_16x16x32_f16.
#define BM 128
#define BN 128
#define BK 32
#define LDSTR 40   // f16 stride: 80B rows -> <=2-way bank aliasing on b128 frag reads (free)

template <typename OT>
__global__ __launch_bounds__(256) void gemm_mfma(
    const __half* __restrict__ A, const __half* __restrict__ Wt,
    const float* __restrict__ bias, OT* __restrict__ C,
    int M, int K, int Nc)
{
    __shared__ _Float16 As[BM][LDSTR];
    __shared__ _Float16 Bs[BN][LDSTR];
    int tid = threadIdx.x;
    int lane = tid & 63, w = tid >> 6;
    int wm = w >> 1, wn = w & 1;
    int quad = lane >> 4, l16 = lane & 15;
    int row0 = blockIdx.x * BM, col0 = blockIdx.y * BN;

    f32x4 acc[4][4];
#pragma unroll
    for (int i = 0; i < 4; i++)
#pragma unroll
        for (int j = 0; j < 4; j++) acc[i][j] = (f32x4){0.f, 0.f, 0.f, 0.f};

    // staging: 2 threads per row, 16 halves (32B = 2x uint4) per thread
    int sr = tid >> 1, sc = (tid & 1) * 16;
    for (int k0 = 0; k0 < K; k0 += BK) {
        uint4 av0 = make_uint4(0, 0, 0, 0), av1 = make_uint4(0, 0, 0, 0);
        uint4 bv0 = make_uint4(0, 0, 0, 0), bv1 = make_uint4(0, 0, 0, 0);
        if (row0 + sr < M) {
            const __half* ap = &A[(size_t)(row0 + sr) * K + k0 + sc];
            av0 = *(const uint4*)ap;
            av1 = *(const uint4*)(ap + 8);
        }
        if (col0 + sr < Nc) {
            const __half* bp = &Wt[(size_t)(col0 + sr) * K + k0 + sc];
            bv0 = *(const uint4*)bp;
            bv1 = *(const uint4*)(bp + 8);
        }
        *(uint4*)&As[sr][sc] = av0;
        *(uint4*)&As[sr][sc + 8] = av1;
        *(uint4*)&Bs[sr][sc] = bv0;
        *(uint4*)&Bs[sr][sc + 8] = bv1;
        __syncthreads();

        half8 af[4], bf[4];
#pragma unroll
        for (int i = 0; i < 4; i++) {
            af[i] = *(half8*)&As[wm * 64 + i * 16 + l16][quad * 8];
            bf[i] = *(half8*)&Bs[wn * 64 + i * 16 + l16][quad * 8];
        }
#pragma unroll
        for (int i = 0; i < 4; i++)
#pragma unroll
            for (int j = 0; j < 4; j++)
                acc[i][j] = __builtin_amdgcn_mfma_f32_16x16x32_f16(af[i], bf[j], acc[i][j], 0, 0, 0);
        __syncthreads();
    }

#pragma unroll
    for (int i = 0; i < 4; i++) {
#pragma unroll
        for (int j = 0; j < 4; j++) {
            int gcol = col0 + wn * 64 + j * 16 + l16;
            if (gcol >= Nc) continue;
            float bb = bias[gcol];
#pragma unroll
            for (int r = 0; r < 4; r++) {
                int grow = row0 + wm * 64 + i * 16 + quad * 4 + r;
                if (grow < M) storeC(&C[(size_t)grow * Nc + gcol], acc[i][j][r] + bb);
            }
        }
    }
}

// ---------------- edge bucketing (counting sort by dst) ----------------
__global__ void count_k(const int* __restrict__ dst, int* __restrict__ counts, int E)
{
    int e = blockIdx.x * 256 + threadIdx.x;
    if (e < E) atomicAdd(&counts[dst[e]], 1);
}

__global__ __launch_bounds__(1024) void scan_k(const int* __restrict__ counts,
                                               int* __restrict__ offs, int n)
{
    __shared__ int wsum[16];
    __shared__ int carry_s;
    int tid = threadIdx.x, lane = tid & 63, wid = tid >> 6;
    if (tid == 0) carry_s = 0;
    __syncthreads();
    for (int base = 0; base < n; base += 1024) {
        int i = base + tid;
        int orig = (i < n) ? counts[i] : 0;
        int v = orig;
#pragma unroll
        for (int d = 1; d < 64; d <<= 1) {
            int t = __shfl_up(v, (unsigned)d, 64);
            if (lane >= d) v += t;
        }
        if (lane == 63) wsum[wid] = v;
        __syncthreads();
        int wpre = 0;
        for (int w2 = 0; w2 < wid; w2++) wpre += wsum[w2];
        if (i < n) offs[i] = carry_s + wpre + v - orig;
        __syncthreads();
        if (tid == 0) {
            int tot = 0;
            for (int w2 = 0; w2 < 16; w2++) tot += wsum[w2];
            carry_s += tot;
        }
        __syncthreads();
    }
    if (tid == 0) offs[n] = carry_s;
}

__global__ void scatter_k(const int* __restrict__ src, const int* __restrict__ dst,
                          const float* __restrict__ attr, const int* __restrict__ offs,
                          int* __restrict__ cursor, int* __restrict__ ssrc,
                          float* __restrict__ sattr, int E)
{
    int e = blockIdx.x * 256 + threadIdx.x;
    if (e < E) {
        int d = dst[e];
        int p = offs[d] + atomicAdd(&cursor[d], 1);
        ssrc[p] = src[e];
        sattr[p] = attr[e];
    }
}

// ---------------- attention: one wave per dst node, online softmax ----------------
// qkvs [N][1024] f16 = q|k|v|skip, 256 each. uint2 = 4 halves; row = 256 uint2.
__global__ __launch_bounds__(256) void attn_k(
    const uint2* __restrict__ qkvs, const float* __restrict__ We,
    float* __restrict__ hwork, const int* __restrict__ ssrc,
    const float* __restrict__ sattr, const int* __restrict__ offs,
    double* __restrict__ stats, int n)
{
    int lane = threadIdx.x & 63;
    int wid = threadIdx.x >> 6;
    int node = blockIdx.x * 4 + wid;
    float lsum = 0.f, lsq = 0.f;
    if (node < n) {
        float4 we = ((const float4*)We)[lane];
        float4 qv = h4_to_f4(qkvs[(size_t)node * 256 + lane]);
        float4 acc = make_float4(0.f, 0.f, 0.f, 0.f);
        float m = -INFINITY, l = 0.f;
        int i0 = offs[node], i1 = offs[node + 1];

        auto process = [&](uint2 kraw, uint2 vraw, float at) {
            float4 kv = h4_to_f4(kraw);
            float p = qv.x * fmaf(at, we.x, kv.x)
                    + qv.y * fmaf(at, we.y, kv.y)
                    + qv.z * fmaf(at, we.z, kv.z)
                    + qv.w * fmaf(at, we.w, kv.w);
            p += __shfl_xor(p, 1);
            p += __shfl_xor(p, 2);
            p += __shfl_xor(p, 4);
            p *= 0.17677669529663687f;   // 1/sqrt(32)
            float mn = fmaxf(m, p);
            float corr = __expf(m - mn);
            float wgt = __expf(p - mn);
            l = l * corr + wgt;
            float4 vv = h4_to_f4(vraw);
            acc.x = fmaf(acc.x, corr, wgt * fmaf(at, we.x, vv.x));
            acc.y = fmaf(acc.y, corr, wgt * fmaf(at, we.y, vv.y));
            acc.z = fmaf(acc.z, corr, wgt * fmaf(at, we.z, vv.z));
            acc.w = fmaf(acc.w, corr, wgt * fmaf(at, we.w, vv.w));
            m = mn;
        };

        int i = i0;
        for (; i + 4 <= i1; i += 4) {
            int s0 = ssrc[i], s1 = ssrc[i + 1], s2 = ssrc[i + 2], s3 = ssrc[i + 3];
            float t0 = sattr[i], t1 = sattr[i + 1], t2 = sattr[i + 2], t3 = sattr[i + 3];
            uint2 k0 = qkvs[(size_t)s0 * 256 + 64 + lane];
            uint2 k1 = qkvs[(size_t)s1 * 256 + 64 + lane];
            uint2 k2 = qkvs[(size_t)s2 * 256 + 64 + lane];
            uint2 k3 = qkvs[(size_t)s3 * 256 + 64 + lane];
            uint2 v0 = qkvs[(size_t)s0 * 256 + 128 + lane];
            uint2 v1 = qkvs[(size_t)s1 * 256 + 128 + lane];
            uint2 v2 = qkvs[(size_t)s2 * 256 + 128 + lane];
            uint2 v3 = qkvs[(size_t)s3 * 256 + 128 + lane];
            process(k0, v0, t0);
            process(k1, v1, t1);
            process(k2, v2, t2);
            process(k3, v3, t3);
        }
        for (; i < i1; i++) {
            int s = ssrc[i];
            float at = sattr[i];
            uint2 kraw = qkvs[(size_t)s * 256 + 64 + lane];
            uint2 vraw = qkvs[(size_t)s * 256 + 128 + lane];
            process(kraw, vraw, at);
        }

        float inv = (l > 0.f) ? 1.f / l : 0.f;
        float4 sk = h4_to_f4(qkvs[(size_t)node * 256 + 192 + lane]);
        float4 o;
        o.x = fmaf(acc.x, inv, sk.x);
        o.y = fmaf(acc.y, inv, sk.y);
        o.z = fmaf(acc.z, inv, sk.z);
        o.w = fmaf(acc.w, inv, sk.w);
        ((float4*)hwork)[(size_t)node * 64 + lane] = o;
        lsum = o.x + o.y + o.z + o.w;
        lsq = o.x * o.x + o.y * o.y + o.z * o.z + o.w * o.w;
    }
#pragma unroll
    for (int d = 1; d < 64; d <<= 1) {
        lsum += __shfl_xor(lsum, d);
        lsq += __shfl_xor(lsq, d);
    }
    __shared__ float red[8];
    if (lane == 0) { red[wid] = lsum; red[4 + wid] = lsq; }
    __syncthreads();
    if (threadIdx.x == 0) {
        double s = (double)red[0] + (double)red[1] + (double)red[2] + (double)red[3];
        double sq = (double)red[4] + (double)red[5] + (double)red[6] + (double)red[7];
        atomicAdd(&stats[0], s);
        atomicAdd(&stats[1], sq);
    }
}

// ---------------- LayerNorm finalize + apply (fp32 in, f16 out) ----------------
__global__ void ln_fin(const double* __restrict__ stats, float* __restrict__ lnp,
                       int idx, double cnt)
{
    if (threadIdx.x == 0 && blockIdx.x == 0) {
        double mean = stats[2 * idx] / cnt;
        double var = stats[2 * idx + 1] / cnt - mean * mean;
        if (var < 0.0) var = 0.0;
        lnp[2 * idx] = (float)mean;
        lnp[2 * idx + 1] = (float)(1.0 / (sqrt(var) + (double)EPSLN));
    }
}

__global__ __launch_bounds__(256) void ln_apply(
    const float4* __restrict__ in, __half* __restrict__ out,
    const float4* __restrict__ w4, const float4* __restrict__ b4,
    const float* __restrict__ lnp, int idx, int total4)
{
    int i = blockIdx.x * 256 + threadIdx.x;
    if (i >= total4) return;
    float mean = lnp[2 * idx], inv = lnp[2 * idx + 1];
    int c = i & 63;
    float4 xv = in[i], w = w4[c], b = b4[c];
    float4 o;
    o.x = fmaf((xv.x - mean) * inv, w.x, b.x);
    o.y = fmaf((xv.y - mean) * inv, w.y, b.y);
    o.z = fmaf((xv.z - mean) * inv, w.z, b.z);
    o.w = fmaf((xv.w - mean) * inv, w.w, b.w);
    o.x = o.x > 0.f ? o.x : expm1f(o.x);
    o.y = o.y > 0.f ? o.y : expm1f(o.y);
    o.z = o.z > 0.f ? o.z : expm1f(o.z);
    o.w = o.w > 0.f ? o.w : expm1f(o.w);
    store4(out + (size_t)i * 4, o);
}

// ---------------- driver ----------------
extern "C" void kernel_launch(void* const* d_in, const int* in_sizes, int n_in,
                              void* d_out, int out_size, void* d_ws, size_t ws_size,
                              hipStream_t stream)
{
    const float* x      = (const float*)d_in[0];
    const int*   ei     = (const int*)d_in[1];
    const float* eattr  = (const float*)d_in[2];
    const float* Wq1 = (const float*)d_in[3];  const float* bq1 = (const float*)d_in[4];
    const float* Wk1 = (const float*)d_in[5];  const float* bk1 = (const float*)d_in[6];
    const float* Wv1 = (const float*)d_in[7];  const float* bv1 = (const float*)d_in[8];
    const float* We1 = (const float*)d_in[9];
    const float* Ws1 = (const float*)d_in[10]; const float* bs1 = (const float*)d_in[11];
    const float* lnw1 = (const float*)d_in[12]; const float* lnb1 = (const float*)d_in[13];
    const float* Wq2 = (const float*)d_in[14]; const float* bq2 = (const float*)d_in[15];
    const float* Wk2 = (const float*)d_in[16]; const float* bk2 = (const float*)d_in[17];
    const float* Wv2 = (const float*)d_in[18]; const float* bv2 = (const float*)d_in[19];
    const float* We2 = (const float*)d_in[20];
    const float* Ws2 = (const float*)d_in[21]; const float* bs2 = (const float*)d_in[22];
    const float* lnw2 = (const float*)d_in[23]; const float* lnb2 = (const float*)d_in[24];
    const float* Wo  = (const float*)d_in[25]; const float* bo  = (const float*)d_in[26];

    const int N = in_sizes[0] / IN_DIM;
    const int E = in_sizes[2];
    const int* esrc = ei;
    const int* edst = ei + E;

    char* ws = (char*)d_ws;
    size_t off = 0;
    auto alloc = [&](size_t bytes) -> char* {
        char* p = ws + off;
        off += (bytes + 255) / 256 * 256;
        return p;
    };
    int*    counts = (int*)alloc((size_t)N * 4);
    int*    cursor = (int*)alloc((size_t)N * 4);
    double* stats  = (double*)alloc(64);
    float*  lnp    = (float*)alloc(256);
    size_t zbytes = off;
    int*    offs   = (int*)alloc((size_t)(N + 1) * 4);
    int*    ssrc   = (int*)alloc((size_t)E * 4);
    float*  sattr  = (float*)alloc((size_t)E * 4);
    __half* xh     = (__half*)alloc((size_t)N * IN_DIM * 2);
    __half* qkvs   = (__half*)alloc((size_t)N * 1024 * 2);
    float*  hwork  = (float*)alloc((size_t)N * HD * 4);
    __half* hio    = (__half*)alloc((size_t)N * HD * 2);
    __half* Wc1    = (__half*)alloc((size_t)1024 * IN_DIM * 2);
    __half* Wc2    = (__half*)alloc((size_t)1024 * HD * 2);
    __half* Wot    = (__half*)alloc((size_t)64 * HD * 2);
    float*  bc1    = (float*)alloc(1024 * 4);
    float*  bc2    = (float*)alloc(1024 * 4);

    hipMemsetAsync(d_ws, 0, zbytes, stream);

    // packing (tiny)
    pack_x_k<<<(N * 32 + 255) / 256, 256, 0, stream>>>((const float4*)x, xh, N * 32);
    pack_wcat_k<<<(1024 * IN_DIM + 255) / 256, 256, 0, stream>>>(Wq1, Wk1, Wv1, Ws1, Wc1, IN_DIM);
    pack_wcat_k<<<(1024 * HD + 255) / 256, 256, 0, stream>>>(Wq2, Wk2, Wv2, Ws2, Wc2, HD);
    pack_bcat_k<<<4, 256, 0, stream>>>(bq1, bk1, bv1, bs1, bc1);
    pack_bcat_k<<<4, 256, 0, stream>>>(bq2, bk2, bv2, bs2, bc2);
    pack_wo_k<<<(64 * HD + 255) / 256, 256, 0, stream>>>(Wo, Wot);

    // edge bucketing
    count_k<<<(E + 255) / 256, 256, 0, stream>>>(edst, counts, E);
    scan_k<<<1, 1024, 0, stream>>>(counts, offs, N);
    scatter_k<<<(E + 255) / 256, 256, 0, stream>>>(esrc, edst, eattr, offs, cursor,
                                                   ssrc, sattr, E);

    dim3 gqkvs((N + BM - 1) / BM, 1024 / BN);
    dim3 gout((N + BM - 1) / BM, 1);
    dim3 ga((N + 3) / 4);
    int total4 = N * (HD / 4);
    dim3 gl((total4 + 255) / 256);

    // ---- layer 1 ----
    gemm_mfma<__half><<<gqkvs, 256, 0, stream>>>(xh, Wc1, bc1, qkvs, N, IN_DIM, 1024);
    attn_k<<<ga, 256, 0, stream>>>((const uint2*)qkvs, We1, hwork, ssrc, sattr,
                                   offs, stats, N);
    ln_fin<<<1, 64, 0, stream>>>(stats, lnp, 0, (double)N * HD);
    ln_apply<<<gl, 256, 0, stream>>>((const float4*)hwork, hio,
                                     (const float4*)lnw1, (const float4*)lnb1,
                                     lnp, 0, total4);

    // ---- layer 2 ----
    gemm_mfma<__half><<<gqkvs, 256, 0, stream>>>(hio, Wc2, bc2, qkvs, N, HD, 1024);
    attn_k<<<ga, 256, 0, stream>>>((const uint2*)qkvs, We2, hwork, ssrc, sattr,
                                   offs, stats + 2, N);
    ln_fin<<<1, 64, 0, stream>>>(stats, lnp, 1, (double)N * HD);
    ln_apply<<<gl, 256, 0, stream>>>((const float4*)hwork, hio,
                                     (const float4*)lnw2, (const float4*)lnb2,
                                     lnp, 1, total4);

    // ---- output projection (fp32 out) ----
    gemm_mfma<float><<<gout, 256, 0, stream>>>(hio, Wot, bo, (float*)d_out, N, HD, 64);
}

// Round 5
// 808.915 us; speedup vs baseline: 2.1626x; 1.4218x over previous
//
#include <hip/hip_runtime.h>
#include <hip/hip_fp16.h>
#include <math.h>

#define IN_DIM 128
#define HD 256
#define EPSLN 1e-5f

typedef _Float16 half8 __attribute__((ext_vector_type(8)));
typedef float f32x4 __attribute__((ext_vector_type(4)));

// ---------------- helpers ----------------
__device__ inline void store4(float* p, float4 o) { *(float4*)p = o; }
__device__ inline void store4(__half* p, float4 o) {
    union { uint2 u; __half2 h[2]; } s;
    s.h[0] = __floats2half2_rn(o.x, o.y);
    s.h[1] = __floats2half2_rn(o.z, o.w);
    *(uint2*)p = s.u;
}
__device__ inline float4 h4_to_f4(uint2 u) {
    union { unsigned int w; __half2 h; } a, b;
    a.w = u.x; b.w = u.y;
    float2 lo = __half22float2(a.h), hi = __half22float2(b.h);
    return make_float4(lo.x, lo.y, hi.x, hi.y);
}
__device__ inline void storeC(__half* p, float v) { *p = __float2half(v); }
__device__ inline void storeC(float* p, float v) { *p = v; }

// Packed output column mapping: q[0:256) | kv-interleaved[256:768) | skip[768:1024)
// kv chunk j (0..63): halves 256+8j..+3 = k[4j..4j+3], 256+8j+4..+7 = v[4j..4j+3]
__device__ inline void unpermute_col(int n, int& sel, int& c) {
    if (n < 256) { sel = 0; c = n; }
    else if (n < 768) {
        int j = n - 256, chunk = j >> 3, w = j & 7;
        if (w < 4) { sel = 1; c = chunk * 4 + w; }
        else       { sel = 2; c = chunk * 4 + w - 4; }
    } else { sel = 3; c = n - 768; }
}

// ---------------- pack kernels (tiny, run every call) ----------------
__global__ void pack_x_k(const float4* __restrict__ x, __half* __restrict__ xh, int total4)
{
    int i = blockIdx.x * 256 + threadIdx.x;
    if (i < total4) store4(xh + (size_t)i * 4, x[i]);
}

// Wt[1024][K] f16 with permuted output columns
__global__ void pack_wcat_k(const float* __restrict__ Wq, const float* __restrict__ Wk,
                            const float* __restrict__ Wv, const float* __restrict__ Ws,
                            __half* __restrict__ Wt, int K)
{
    int idx = blockIdx.x * 256 + threadIdx.x;
    if (idx >= 1024 * K) return;
    int n = idx / K, k = idx % K;
    int sel, c;
    unpermute_col(n, sel, c);
    const float* W = (sel == 0) ? Wq : (sel == 1) ? Wk : (sel == 2) ? Wv : Ws;
    Wt[idx] = __float2half(W[(size_t)k * 256 + c]);
}

__global__ void pack_bcat_k(const float* __restrict__ bq, const float* __restrict__ bk,
                            const float* __restrict__ bv, const float* __restrict__ bs,
                            float* __restrict__ bcat)
{
    int n = blockIdx.x * 256 + threadIdx.x;
    if (n >= 1024) return;
    int sel, c;
    unpermute_col(n, sel, c);
    const float* b = (sel == 0) ? bq : (sel == 1) ? bk : (sel == 2) ? bv : bs;
    bcat[n] = b[c];
}

// Wo_t[64][256] from Wo[256][64]
__global__ void pack_wo_k(const float* __restrict__ Wo, __half* __restrict__ Wot)
{
    int idx = blockIdx.x * 256 + threadIdx.x;
    if (idx >= 64 * 256) return;
    int n = idx >> 8, k = idx & 255;
    Wot[idx] = __float2half(Wo[(size_t)k * 64 + n]);
}

// ---------------- MFMA GEMM: C[M x Nc] = A[M x K] @ Wt^T + bias ----------------
#define BM 128
#define BN 128
#define BK 32
#define LDSTR 40

template <typename OT>
__global__ __launch_bounds__(256) void gemm_mfma(
    const __half* __restrict__ A, const __half* __restrict__ Wt,
    const float* __restrict__ bias, OT* __restrict__ C,
    int M, int K, int Nc)
{
    __shared__ _Float16 As[BM][LDSTR];
    __shared__ _Float16 Bs[BN][LDSTR];
    int tid = threadIdx.x;
    int lane = tid & 63, w = tid >> 6;
    int wm = w >> 1, wn = w & 1;
    int quad = lane >> 4, l16 = lane & 15;
    int row0 = blockIdx.x * BM, col0 = blockIdx.y * BN;

    f32x4 acc[4][4];
#pragma unroll
    for (int i = 0; i < 4; i++)
#pragma unroll
        for (int j = 0; j < 4; j++) acc[i][j] = (f32x4){0.f, 0.f, 0.f, 0.f};

    int sr = tid >> 1, sc = (tid & 1) * 16;
    for (int k0 = 0; k0 < K; k0 += BK) {
        uint4 av0 = make_uint4(0, 0, 0, 0), av1 = make_uint4(0, 0, 0, 0);
        uint4 bv0 = make_uint4(0, 0, 0, 0), bv1 = make_uint4(0, 0, 0, 0);
        if (row0 + sr < M) {
            const __half* ap = &A[(size_t)(row0 + sr) * K + k0 + sc];
            av0 = *(const uint4*)ap;
            av1 = *(const uint4*)(ap + 8);
        }
        if (col0 + sr < Nc) {
            const __half* bp = &Wt[(size_t)(col0 + sr) * K + k0 + sc];
            bv0 = *(const uint4*)bp;
            bv1 = *(const uint4*)(bp + 8);
        }
        *(uint4*)&As[sr][sc] = av0;
        *(uint4*)&As[sr][sc + 8] = av1;
        *(uint4*)&Bs[sr][sc] = bv0;
        *(uint4*)&Bs[sr][sc + 8] = bv1;
        __syncthreads();

        half8 af[4], bf[4];
#pragma unroll
        for (int i = 0; i < 4; i++) {
            af[i] = *(half8*)&As[wm * 64 + i * 16 + l16][quad * 8];
            bf[i] = *(half8*)&Bs[wn * 64 + i * 16 + l16][quad * 8];
        }
#pragma unroll
        for (int i = 0; i < 4; i++)
#pragma unroll
            for (int j = 0; j < 4; j++)
                acc[i][j] = __builtin_amdgcn_mfma_f32_16x16x32_f16(af[i], bf[j], acc[i][j], 0, 0, 0);
        __syncthreads();
    }

#pragma unroll
    for (int i = 0; i < 4; i++) {
#pragma unroll
        for (int j = 0; j < 4; j++) {
            int gcol = col0 + wn * 64 + j * 16 + l16;
            if (gcol >= Nc) continue;
            float bb = bias[gcol];
#pragma unroll
            for (int r = 0; r < 4; r++) {
                int grow = row0 + wm * 64 + i * 16 + quad * 4 + r;
                if (grow < M) storeC(&C[(size_t)grow * Nc + gcol], acc[i][j][r] + bb);
            }
        }
    }
}

// ---------------- edge bucketing (counting sort by dst) ----------------
__global__ void count_k(const int* __restrict__ dst, int* __restrict__ counts, int E)
{
    int e = blockIdx.x * 256 + threadIdx.x;
    if (e < E) atomicAdd(&counts[dst[e]], 1);
}

// one-pass thread-coarsened exclusive scan, single block of 1024
__global__ __launch_bounds__(1024) void scan_k(const int* __restrict__ counts,
                                               int* __restrict__ offs, int n)
{
    __shared__ int wsum[16];
    __shared__ int wpre[16];
    int tid = threadIdx.x, lane = tid & 63, wid = tid >> 6;
    int per = (n + 1023) / 1024;
    int start = tid * per, end = min(start + per, n);
    int sum = 0;
    for (int i = start; i < end; i++) sum += counts[i];
    // inclusive wave scan
    int v = sum;
#pragma unroll
    for (int d = 1; d < 64; d <<= 1) {
        int t = __shfl_up(v, (unsigned)d, 64);
        if (lane >= d) v += t;
    }
    if (lane == 63) wsum[wid] = v;
    __syncthreads();
    if (tid == 0) {
        int acc = 0;
        for (int i = 0; i < 16; i++) { wpre[i] = acc; acc += wsum[i]; }
    }
    __syncthreads();
    int pre = wpre[wid] + v - sum;   // exclusive prefix for this thread
    for (int i = start; i < end; i++) { offs[i] = pre; pre += counts[i]; }
    if (tid == 1023 || end == n) {
        if (end == n && start <= n) offs[n] = pre;
    }
}

__global__ void scatter_k(const int* __restrict__ src, const int* __restrict__ dst,
                          const float* __restrict__ attr, const int* __restrict__ offs,
                          int* __restrict__ cursor, int2* __restrict__ edat, int E)
{
    int e = blockIdx.x * 256 + threadIdx.x;
    if (e < E) {
        int d = dst[e];
        int p = offs[d] + atomicAdd(&cursor[d], 1);
        edat[p] = make_int2(src[e], __float_as_int(attr[e]));
    }
}

// ---------------- attention: one wave per dst node, online softmax ----------------
// qkvs [N][1024] halves = q[256] | kv-interleaved[512] | skip[256].
// lane owns channels 4*lane..4*lane+3; kv uint4 at row-uint4-index 32+lane.
__global__ __launch_bounds__(256) void attn_k(
    const uint2* __restrict__ q2, const uint4* __restrict__ kv4,
    const float* __restrict__ We,
    float* __restrict__ hwork, const int2* __restrict__ edat,
    const int* __restrict__ offs,
    double* __restrict__ stats, int n, int nGroups)
{
    int lane = threadIdx.x & 63;
    int wid = threadIdx.x >> 6;
    float4 we = ((const float4*)We)[lane];
    float tsum = 0.f, tsq = 0.f;

    for (int g = blockIdx.x; g < nGroups; g += gridDim.x) {
        int node = g * 4 + wid;
        if (node >= n) continue;
        float4 qv = h4_to_f4(q2[(size_t)node * 256 + lane]);
        float4 acc = make_float4(0.f, 0.f, 0.f, 0.f);
        float m = -INFINITY, l = 0.f;
        int i0 = offs[node], i1 = offs[node + 1];

        auto proc = [&](uint4 kvraw, float at) {
            float4 kv = h4_to_f4(make_uint2(kvraw.x, kvraw.y));
            float p = qv.x * fmaf(at, we.x, kv.x)
                    + qv.y * fmaf(at, we.y, kv.y)
                    + qv.z * fmaf(at, we.z, kv.z)
                    + qv.w * fmaf(at, we.w, kv.w);
            p += __shfl_xor(p, 1);
            p += __shfl_xor(p, 2);
            p += __shfl_xor(p, 4);
            p *= 0.17677669529663687f;   // 1/sqrt(32)
            float mn = fmaxf(m, p);
            float corr = __expf(m - mn);
            float wgt = __expf(p - mn);
            l = l * corr + wgt;
            float4 vv = h4_to_f4(make_uint2(kvraw.z, kvraw.w));
            acc.x = fmaf(acc.x, corr, wgt * fmaf(at, we.x, vv.x));
            acc.y = fmaf(acc.y, corr, wgt * fmaf(at, we.y, vv.y));
            acc.z = fmaf(acc.z, corr, wgt * fmaf(at, we.z, vv.z));
            acc.w = fmaf(acc.w, corr, wgt * fmaf(at, we.w, vv.w));
            m = mn;
        };

        int i = i0;
        for (; i + 8 <= i1; i += 8) {
            int2 ed[8];
#pragma unroll
            for (int u = 0; u < 8; u++) ed[u] = edat[i + u];
            uint4 kvv[8];
#pragma unroll
            for (int u = 0; u < 8; u++)
                kvv[u] = kv4[(size_t)ed[u].x * 128 + 32 + lane];
#pragma unroll
            for (int u = 0; u < 8; u++) proc(kvv[u], __int_as_float(ed[u].y));
        }
        for (; i < i1; i++) {
            int2 ed = edat[i];
            uint4 kvraw = kv4[(size_t)ed.x * 128 + 32 + lane];
            proc(kvraw, __int_as_float(ed.y));
        }

        float inv = (l > 0.f) ? 1.f / l : 0.f;
        float4 sk = h4_to_f4(q2[(size_t)node * 256 + 192 + lane]);
        float4 o;
        o.x = fmaf(acc.x, inv, sk.x);
        o.y = fmaf(acc.y, inv, sk.y);
        o.z = fmaf(acc.z, inv, sk.z);
        o.w = fmaf(acc.w, inv, sk.w);
        ((float4*)hwork)[(size_t)node * 64 + lane] = o;
        tsum += o.x + o.y + o.z + o.w;
        tsq += o.x * o.x + o.y * o.y + o.z * o.z + o.w * o.w;
    }

#pragma unroll
    for (int d = 1; d < 64; d <<= 1) {
        tsum += __shfl_xor(tsum, d);
        tsq += __shfl_xor(tsq, d);
    }
    __shared__ float red[8];
    if (lane == 0) { red[wid] = tsum; red[4 + wid] = tsq; }
    __syncthreads();
    if (threadIdx.x == 0) {
        double s = (double)red[0] + (double)red[1] + (double)red[2] + (double)red[3];
        double sq = (double)red[4] + (double)red[5] + (double)red[6] + (double)red[7];
        atomicAdd(&stats[0], s);
        atomicAdd(&stats[1], sq);
    }
}

// ---------------- LayerNorm finalize + apply (fp32 in, f16 out) ----------------
__global__ void ln_fin(const double* __restrict__ stats, float* __restrict__ lnp,
                       int idx, double cnt)
{
    if (threadIdx.x == 0 && blockIdx.x == 0) {
        double mean = stats[2 * idx] / cnt;
        double var = stats[2 * idx + 1] / cnt - mean * mean;
        if (var < 0.0) var = 0.0;
        lnp[2 * idx] = (float)mean;
        lnp[2 * idx + 1] = (float)(1.0 / (sqrt(var) + (double)EPSLN));
    }
}

__global__ __launch_bounds__(256) void ln_apply(
    const float4* __restrict__ in, __half* __restrict__ out,
    const float4* __restrict__ w4, const float4* __restrict__ b4,
    const float* __restrict__ lnp, int idx, int total4)
{
    int i = blockIdx.x * 256 + threadIdx.x;
    if (i >= total4) return;
    float mean = lnp[2 * idx], inv = lnp[2 * idx + 1];
    int c = i & 63;
    float4 xv = in[i], w = w4[c], b = b4[c];
    float4 o;
    o.x = fmaf((xv.x - mean) * inv, w.x, b.x);
    o.y = fmaf((xv.y - mean) * inv, w.y, b.y);
    o.z = fmaf((xv.z - mean) * inv, w.z, b.z);
    o.w = fmaf((xv.w - mean) * inv, w.w, b.w);
    o.x = o.x > 0.f ? o.x : expm1f(o.x);
    o.y = o.y > 0.f ? o.y : expm1f(o.y);
    o.z = o.z > 0.f ? o.z : expm1f(o.z);
    o.w = o.w > 0.f ? o.w : expm1f(o.w);
    store4(out + (size_t)i * 4, o);
}

// ---------------- driver ----------------
extern "C" void kernel_launch(void* const* d_in, const int* in_sizes, int n_in,
                              void* d_out, int out_size, void* d_ws, size_t ws_size,
                              hipStream_t stream)
{
    const float* x      = (const float*)d_in[0];
    const int*   ei     = (const int*)d_in[1];
    const float* eattr  = (const float*)d_in[2];
    const float* Wq1 = (const float*)d_in[3];  const float* bq1 = (const float*)d_in[4];
    const float* Wk1 = (const float*)d_in[5];  const float* bk1 = (const float*)d_in[6];
    const float* Wv1 = (const float*)d_in[7];  const float* bv1 = (const float*)d_in[8];
    const float* We1 = (const float*)d_in[9];
    const float* Ws1 = (const float*)d_in[10]; const float* bs1 = (const float*)d_in[11];
    const float* lnw1 = (const float*)d_in[12]; const float* lnb1 = (const float*)d_in[13];
    const float* Wq2 = (const float*)d_in[14]; const float* bq2 = (const float*)d_in[15];
    const float* Wk2 = (const float*)d_in[16]; const float* bk2 = (const float*)d_in[17];
    const float* Wv2 = (const float*)d_in[18]; const float* bv2 = (const float*)d_in[19];
    const float* We2 = (const float*)d_in[20];
    const float* Ws2 = (const float*)d_in[21]; const float* bs2 = (const float*)d_in[22];
    const float* lnw2 = (const float*)d_in[23]; const float* lnb2 = (const float*)d_in[24];
    const float* Wo  = (const float*)d_in[25]; const float* bo  = (const float*)d_in[26];

    const int N = in_sizes[0] / IN_DIM;
    const int E = in_sizes[2];
    const int* esrc = ei;
    const int* edst = ei + E;

    char* ws = (char*)d_ws;
    size_t off = 0;
    auto alloc = [&](size_t bytes) -> char* {
        char* p = ws + off;
        off += (bytes + 255) / 256 * 256;
        return p;
    };
    int*    counts = (int*)alloc((size_t)N * 4);
    int*    cursor = (int*)alloc((size_t)N * 4);
    double* stats  = (double*)alloc(64);
    float*  lnp    = (float*)alloc(256);
    size_t zbytes = off;
    int*    offs   = (int*)alloc((size_t)(N + 1) * 4);
    int2*   edat   = (int2*)alloc((size_t)E * 8);
    __half* xh     = (__half*)alloc((size_t)N * IN_DIM * 2);
    __half* qkvs   = (__half*)alloc((size_t)N * 1024 * 2);
    float*  hwork  = (float*)alloc((size_t)N * HD * 4);
    __half* hio    = (__half*)alloc((size_t)N * HD * 2);
    __half* Wc1    = (__half*)alloc((size_t)1024 * IN_DIM * 2);
    __half* Wc2    = (__half*)alloc((size_t)1024 * HD * 2);
    __half* Wot    = (__half*)alloc((size_t)64 * HD * 2);
    float*  bc1    = (float*)alloc(1024 * 4);
    float*  bc2    = (float*)alloc(1024 * 4);

    hipMemsetAsync(d_ws, 0, zbytes, stream);

    // packing (tiny)
    pack_x_k<<<(N * 32 + 255) / 256, 256, 0, stream>>>((const float4*)x, xh, N * 32);
    pack_wcat_k<<<(1024 * IN_DIM + 255) / 256, 256, 0, stream>>>(Wq1, Wk1, Wv1, Ws1, Wc1, IN_DIM);
    pack_wcat_k<<<(1024 * HD + 255) / 256, 256, 0, stream>>>(Wq2, Wk2, Wv2, Ws2, Wc2, HD);
    pack_bcat_k<<<4, 256, 0, stream>>>(bq1, bk1, bv1, bs1, bc1);
    pack_bcat_k<<<4, 256, 0, stream>>>(bq2, bk2, bv2, bs2, bc2);
    pack_wo_k<<<(64 * HD + 255) / 256, 256, 0, stream>>>(Wo, Wot);

    // edge bucketing
    count_k<<<(E + 255) / 256, 256, 0, stream>>>(edst, counts, E);
    scan_k<<<1, 1024, 0, stream>>>(counts, offs, N);
    scatter_k<<<(E + 255) / 256, 256, 0, stream>>>(esrc, edst, eattr, offs, cursor,
                                                   edat, E);

    dim3 gqkvs((N + BM - 1) / BM, 1024 / BN);
    dim3 gout((N + BM - 1) / BM, 1);
    int nGroups = (N + 3) / 4;
    int gaBlocks = nGroups < 2048 ? nGroups : 2048;
    int total4 = N * (HD / 4);
    dim3 gl((total4 + 255) / 256);

    // ---- layer 1 ----
    gemm_mfma<__half><<<gqkvs, 256, 0, stream>>>(xh, Wc1, bc1, qkvs, N, IN_DIM, 1024);
    attn_k<<<gaBlocks, 256, 0, stream>>>((const uint2*)qkvs, (const uint4*)qkvs, We1,
                                         hwork, edat, offs, stats, N, nGroups);
    ln_fin<<<1, 64, 0, stream>>>(stats, lnp, 0, (double)N * HD);
    ln_apply<<<gl, 256, 0, stream>>>((const float4*)hwork, hio,
                                     (const float4*)lnw1, (const float4*)lnb1,
                                     lnp, 0, total4);

    // ---- layer 2 ----
    gemm_mfma<__half><<<gqkvs, 256, 0, stream>>>(hio, Wc2, bc2, qkvs, N, HD, 1024);
    attn_k<<<gaBlocks, 256, 0, stream>>>((const uint2*)qkvs, (const uint4*)qkvs, We2,
                                         hwork, edat, offs, stats + 2, N, nGroups);
    ln_fin<<<1, 64, 0, stream>>>(stats, lnp, 1, (double)N * HD);
    ln_apply<<<gl, 256, 0, stream>>>((const float4*)hwork, hio,
                                     (const float4*)lnw2, (const float4*)lnb2,
                                     lnp, 1, total4);

    // ---- output projection (fp32 out) ----
    gemm_mfma<float><<<gout, 256, 0, stream>>>(hio, Wot, bo, (float*)d_out, N, HD, 64);
}

// Round 7
// 751.635 us; speedup vs baseline: 2.3274x; 1.0762x over previous
//
#include <hip/hip_runtime.h>
#include <hip/hip_fp16.h>
#include <math.h>

#define IN_DIM 128
#define HD 256
#define EPSLN 1e-5f

typedef _Float16 half8 __attribute__((ext_vector_type(8)));
typedef float f32x4 __attribute__((ext_vector_type(4)));

// ---------------- helpers ----------------
__device__ inline void store4(float* p, float4 o) { *(float4*)p = o; }
__device__ inline void store4(__half* p, float4 o) {
    union { uint2 u; __half2 h[2]; } s;
    s.h[0] = __floats2half2_rn(o.x, o.y);
    s.h[1] = __floats2half2_rn(o.z, o.w);
    *(uint2*)p = s.u;
}
__device__ inline float4 h4_to_f4(uint2 u) {
    union { unsigned int w; __half2 h; } a, b;
    a.w = u.x; b.w = u.y;
    float2 lo = __half22float2(a.h), hi = __half22float2(b.h);
    return make_float4(lo.x, lo.y, hi.x, hi.y);
}

// Packed output column mapping: q[0:256) | kv-interleaved[256:768) | skip[768:1024)
__device__ inline void unpermute_col(int n, int& sel, int& c) {
    if (n < 256) { sel = 0; c = n; }
    else if (n < 768) {
        int j = n - 256, chunk = j >> 3, w = j & 7;
        if (w < 4) { sel = 1; c = chunk * 4 + w; }
        else       { sel = 2; c = chunk * 4 + w - 4; }
    } else { sel = 3; c = n - 768; }
}

// ---------------- pack kernels ----------------
__global__ void pack_x_k(const float4* __restrict__ x, __half* __restrict__ xh, int total4)
{
    int i = blockIdx.x * 256 + threadIdx.x;
    if (i < total4) store4(xh + (size_t)i * 4, x[i]);
}

__global__ void pack_wcat_k(const float* __restrict__ Wq, const float* __restrict__ Wk,
                            const float* __restrict__ Wv, const float* __restrict__ Ws,
                            __half* __restrict__ Wt, int K)
{
    int idx = blockIdx.x * 256 + threadIdx.x;
    if (idx >= 1024 * K) return;
    int n = idx / K, k = idx % K;
    int sel, c;
    unpermute_col(n, sel, c);
    const float* W = (sel == 0) ? Wq : (sel == 1) ? Wk : (sel == 2) ? Wv : Ws;
    Wt[idx] = __float2half(W[(size_t)k * 256 + c]);
}

__global__ void pack_bcat_k(const float* __restrict__ bq, const float* __restrict__ bk,
                            const float* __restrict__ bv, const float* __restrict__ bs,
                            float* __restrict__ bcat)
{
    int n = blockIdx.x * 256 + threadIdx.x;
    if (n >= 1024) return;
    int sel, c;
    unpermute_col(n, sel, c);
    const float* b = (sel == 0) ? bq : (sel == 1) ? bk : (sel == 2) ? bv : bs;
    bcat[n] = b[c];
}

__global__ void pack_wo_k(const float* __restrict__ Wo, __half* __restrict__ Wot)
{
    int idx = blockIdx.x * 256 + threadIdx.x;
    if (idx >= 64 * 256) return;
    int n = idx >> 8, k = idx & 255;
    Wot[idx] = __float2half(Wo[(size_t)k * 64 + n]);
}

// ---------------- MFMA GEMM: C[M x Nc] = A[M x K] @ Wt^T + bias ----------------
#define BM 128
#define BN 128
#define BK 32
#define LDSTR 40
// f16 out-tile LDS row stride: 272 bytes (holds 128 halves = 256B; 16B-aligned, bank-staggered)
#define TROWB 272

template <typename OT>
__global__ __launch_bounds__(256) void gemm_mfma(
    const __half* __restrict__ A, const __half* __restrict__ Wt,
    const float* __restrict__ bias, OT* __restrict__ C,
    int M, int K, int Nc)
{
    __shared__ char smem[BM * TROWB];   // 34 KB; As|Bs during K-loop, f16 out-tile after
    _Float16 (*As)[LDSTR] = (_Float16(*)[LDSTR])smem;
    _Float16 (*Bs)[LDSTR] = (_Float16(*)[LDSTR])(smem + BM * LDSTR * 2);

    int tid = threadIdx.x;
    int lane = tid & 63, w = tid >> 6;
    int wm = w >> 1, wn = w & 1;
    int quad = lane >> 4, l16 = lane & 15;
    int row0 = blockIdx.x * BM, col0 = blockIdx.y * BN;

    f32x4 acc[4][4];
#pragma unroll
    for (int i = 0; i < 4; i++)
#pragma unroll
        for (int j = 0; j < 4; j++) acc[i][j] = (f32x4){0.f, 0.f, 0.f, 0.f};

    int sr = tid >> 1, sc = (tid & 1) * 16;
    for (int k0 = 0; k0 < K; k0 += BK) {
        uint4 av0 = make_uint4(0, 0, 0, 0), av1 = make_uint4(0, 0, 0, 0);
        uint4 bv0 = make_uint4(0, 0, 0, 0), bv1 = make_uint4(0, 0, 0, 0);
        if (row0 + sr < M) {
            const __half* ap = &A[(size_t)(row0 + sr) * K + k0 + sc];
            av0 = *(const uint4*)ap;
            av1 = *(const uint4*)(ap + 8);
        }
        if (col0 + sr < Nc) {
            const __half* bp = &Wt[(size_t)(col0 + sr) * K + k0 + sc];
            bv0 = *(const uint4*)bp;
            bv1 = *(const uint4*)(bp + 8);
        }
        *(uint4*)&As[sr][sc] = av0;
        *(uint4*)&As[sr][sc + 8] = av1;
        *(uint4*)&Bs[sr][sc] = bv0;
        *(uint4*)&Bs[sr][sc + 8] = bv1;
        __syncthreads();

        half8 af[4], bf[4];
#pragma unroll
        for (int i = 0; i < 4; i++) {
            af[i] = *(half8*)&As[wm * 64 + i * 16 + l16][quad * 8];
            bf[i] = *(half8*)&Bs[wn * 64 + i * 16 + l16][quad * 8];
        }
#pragma unroll
        for (int i = 0; i < 4; i++)
#pragma unroll
            for (int j = 0; j < 4; j++)
                acc[i][j] = __builtin_amdgcn_mfma_f32_16x16x32_f16(af[i], bf[j], acc[i][j], 0, 0, 0);
        __syncthreads();   // also guards the As/Bs -> out-tile alias
    }

    if constexpr (sizeof(OT) == 2) {
        // f16 path: stage tile in LDS, then fully-coalesced 16B copy-out
#pragma unroll
        for (int j = 0; j < 4; j++) {
            int tcol = wn * 64 + j * 16 + l16;
            float bb = (col0 + tcol < Nc) ? bias[col0 + tcol] : 0.f;
#pragma unroll
            for (int i = 0; i < 4; i++) {
#pragma unroll
                for (int r = 0; r < 4; r++) {
                    int trow = wm * 64 + i * 16 + quad * 4 + r;
                    ((__half*)(smem + trow * TROWB))[tcol] = __float2half(acc[i][j][r] + bb);
                }
            }
        }
        __syncthreads();
        // 16 chunks/row (16B each), 16 rows per pass, 8 passes
        int crow = tid >> 4, cchunk = tid & 15;
        for (int p = 0; p < 8; p++) {
            int trow = p * 16 + crow;
            int grow = row0 + trow;
            int gcol = cchunk * 8;
            if (grow < M && col0 + gcol < Nc) {
                uint4 val = *(uint4*)(smem + trow * TROWB + cchunk * 16);
                *(uint4*)&((__half*)C)[(size_t)grow * Nc + col0 + gcol] = val;
            }
        }
    } else {
        // fp32 path (small output GEMM): direct stores
#pragma unroll
        for (int i = 0; i < 4; i++) {
#pragma unroll
            for (int j = 0; j < 4; j++) {
                int gcol = col0 + wn * 64 + j * 16 + l16;
                if (gcol >= Nc) continue;
                float bb = bias[gcol];
#pragma unroll
                for (int r = 0; r < 4; r++) {
                    int grow = row0 + wm * 64 + i * 16 + quad * 4 + r;
                    if (grow < M) ((float*)C)[(size_t)grow * Nc + gcol] = acc[i][j][r] + bb;
                }
            }
        }
    }
}

// ---------------- edge bucketing (counting sort by dst) ----------------
__global__ void count_k(const int* __restrict__ dst, int* __restrict__ counts, int E)
{
    int e = blockIdx.x * 256 + threadIdx.x;
    if (e < E) atomicAdd(&counts[dst[e]], 1);
}

__global__ __launch_bounds__(1024) void scan_k(const int* __restrict__ counts,
                                               int* __restrict__ offs, int n)
{
    __shared__ int wsum[16];
    __shared__ int wpre[16];
    int tid = threadIdx.x, lane = tid & 63, wid = tid >> 6;
    int per = (n + 1023) / 1024;
    int start = tid * per, end = min(start + per, n);
    int sum = 0;
    for (int i = start; i < end; i++) sum += counts[i];
    int v = sum;
#pragma unroll
    for (int d = 1; d < 64; d <<= 1) {
        int t = __shfl_up(v, (unsigned)d, 64);
        if (lane >= d) v += t;
    }
    if (lane == 63) wsum[wid] = v;
    __syncthreads();
    if (tid == 0) {
        int acc = 0;
        for (int i = 0; i < 16; i++) { wpre[i] = acc; acc += wsum[i]; }
    }
    __syncthreads();
    int pre = wpre[wid] + v - sum;
    for (int i = start; i < end; i++) { offs[i] = pre; pre += counts[i]; }
    if (end == n && start <= n) offs[n] = pre;
}

__global__ void scatter_k(const int* __restrict__ src, const int* __restrict__ dst,
                          const float* __restrict__ attr, const int* __restrict__ offs,
                          int* __restrict__ cursor, int2* __restrict__ edat, int E)
{
    int e = blockIdx.x * 256 + threadIdx.x;
    if (e < E) {
        int d = dst[e];
        int p = offs[d] + atomicAdd(&cursor[d], 1);
        edat[p] = make_int2(src[e], __float_as_int(attr[e]));
    }
}

// ---------------- attention: one wave per dst node, online softmax ----------------
// qkvs [N][1024] halves = q[256] | kv-interleaved[512] | skip[256].
__global__ __launch_bounds__(256) void attn_k(
    const uint2* __restrict__ q2, const uint4* __restrict__ kv4,
    const float* __restrict__ We,
    float* __restrict__ hwork, const int2* __restrict__ edat,
    const int* __restrict__ offs,
    double* __restrict__ stats, int n, int nGroups)
{
    int lane = threadIdx.x & 63;
    int wid = threadIdx.x >> 6;
    float4 we = ((const float4*)We)[lane];
    float tsum = 0.f, tsq = 0.f;

    for (int g = blockIdx.x; g < nGroups; g += gridDim.x) {
        int node = g * 4 + wid;
        if (node >= n) continue;
        float4 qv = h4_to_f4(q2[(size_t)node * 256 + lane]);
        float qwe = qv.x * we.x + qv.y * we.y + qv.z * we.z + qv.w * we.w;
        qwe += __shfl_xor(qwe, 1);
        qwe += __shfl_xor(qwe, 2);
        qwe += __shfl_xor(qwe, 4);

        float4 accv = make_float4(0.f, 0.f, 0.f, 0.f);
        float sat = 0.f;
        float m = -INFINITY, l = 0.f;
        int i0 = offs[node], i1 = offs[node + 1];

        auto proc = [&](uint4 kvraw, float at) {
            float4 kv = h4_to_f4(make_uint2(kvraw.x, kvraw.y));
            float p = qv.x * kv.x + qv.y * kv.y + qv.z * kv.z + qv.w * kv.w;
            p += __shfl_xor(p, 1);
            p += __shfl_xor(p, 2);
            p += __shfl_xor(p, 4);
            p = fmaf(at, qwe, p) * 0.17677669529663687f;   // (q.k + at*q.we)/sqrt(32)
            float mn = fmaxf(m, p);
            float corr = __expf(m - mn);
            float wgt = __expf(p - mn);
            l = l * corr + wgt;
            sat = fmaf(sat, corr, wgt * at);
            float4 vv = h4_to_f4(make_uint2(kvraw.z, kvraw.w));
            accv.x = fmaf(accv.x, corr, wgt * vv.x);
            accv.y = fmaf(accv.y, corr, wgt * vv.y);
            accv.z = fmaf(accv.z, corr, wgt * vv.z);
            accv.w = fmaf(accv.w, corr, wgt * vv.w);
            m = mn;
        };

        int i = i0;
        for (; i + 8 <= i1; i += 8) {
            int2 ed[8];
#pragma unroll
            for (int u = 0; u < 8; u++) ed[u] = edat[i + u];
            uint4 kvv[8];
#pragma unroll
            for (int u = 0; u < 8; u++)
                kvv[u] = kv4[(size_t)ed[u].x * 128 + 32 + lane];
#pragma unroll
            for (int u = 0; u < 8; u++) proc(kvv[u], __int_as_float(ed[u].y));
        }
        for (; i < i1; i++) {
            int2 ed = edat[i];
            uint4 kvraw = kv4[(size_t)ed.x * 128 + 32 + lane];
            proc(kvraw, __int_as_float(ed.y));
        }

        float inv = (l > 0.f) ? 1.f / l : 0.f;
        float4 sk = h4_to_f4(q2[(size_t)node * 256 + 192 + lane]);
        float sw = sat * inv;
        float4 o;
        o.x = fmaf(accv.x, inv, fmaf(sw, we.x, sk.x));
        o.y = fmaf(accv.y, inv, fmaf(sw, we.y, sk.y));
        o.z = fmaf(accv.z, inv, fmaf(sw, we.z, sk.z));
        o.w = fmaf(accv.w, inv, fmaf(sw, we.w, sk.w));
        ((float4*)hwork)[(size_t)node * 64 + lane] = o;
        tsum += o.x + o.y + o.z + o.w;
        tsq += o.x * o.x + o.y * o.y + o.z * o.z + o.w * o.w;
    }

#pragma unroll
    for (int d = 1; d < 64; d <<= 1) {
        tsum += __shfl_xor(tsum, d);
        tsq += __shfl_xor(tsq, d);
    }
    __shared__ float red[8];
    if (lane == 0) { red[wid] = tsum; red[4 + wid] = tsq; }
    __syncthreads();
    if (threadIdx.x == 0) {
        double s = (double)red[0] + (double)red[1] + (double)red[2] + (double)red[3];
        double sq = (double)red[4] + (double)red[5] + (double)red[6] + (double)red[7];
        atomicAdd(&stats[0], s);
        atomicAdd(&stats[1], sq);
    }
}

// ---------------- LayerNorm finalize + apply ----------------
__global__ void ln_fin(const double* __restrict__ stats, float* __restrict__ lnp,
                       int idx, double cnt)
{
    if (threadIdx.x == 0 && blockIdx.x == 0) {
        double mean = stats[2 * idx] / cnt;
        double var = stats[2 * idx + 1] / cnt - mean * mean;
        if (var < 0.0) var = 0.0;
        lnp[2 * idx] = (float)mean;
        lnp[2 * idx + 1] = (float)(1.0 / (sqrt(var) + (double)EPSLN));
    }
}

__global__ __launch_bounds__(256) void ln_apply(
    const float4* __restrict__ in, __half* __restrict__ out,
    const float4* __restrict__ w4, const float4* __restrict__ b4,
    const float* __restrict__ lnp, int idx, int total4)
{
    int i = blockIdx.x * 256 + threadIdx.x;
    if (i >= total4) return;
    float mean = lnp[2 * idx], inv = lnp[2 * idx + 1];
    int c = i & 63;
    float4 xv = in[i], w = w4[c], b = b4[c];
    float4 o;
    o.x = fmaf((xv.x - mean) * inv, w.x, b.x);
    o.y = fmaf((xv.y - mean) * inv, w.y, b.y);
    o.z = fmaf((xv.z - mean) * inv, w.z, b.z);
    o.w = fmaf((xv.w - mean) * inv, w.w, b.w);
    o.x = o.x > 0.f ? o.x : expm1f(o.x);
    o.y = o.y > 0.f ? o.y : expm1f(o.y);
    o.z = o.z > 0.f ? o.z : expm1f(o.z);
    o.w = o.w > 0.f ? o.w : expm1f(o.w);
    store4(out + (size_t)i * 4, o);
}

// ---------------- driver ----------------
extern "C" void kernel_launch(void* const* d_in, const int* in_sizes, int n_in,
                              void* d_out, int out_size, void* d_ws, size_t ws_size,
                              hipStream_t stream)
{
    const float* x      = (const float*)d_in[0];
    const int*   ei     = (const int*)d_in[1];
    const float* eattr  = (const float*)d_in[2];
    const float* Wq1 = (const float*)d_in[3];  const float* bq1 = (const float*)d_in[4];
    const float* Wk1 = (const float*)d_in[5];  const float* bk1 = (const float*)d_in[6];
    const float* Wv1 = (const float*)d_in[7];  const float* bv1 = (const float*)d_in[8];
    const float* We1 = (const float*)d_in[9];
    const float* Ws1 = (const float*)d_in[10]; const float* bs1 = (const float*)d_in[11];
    const float* lnw1 = (const float*)d_in[12]; const float* lnb1 = (const float*)d_in[13];
    const float* Wq2 = (const float*)d_in[14]; const float* bq2 = (const float*)d_in[15];
    const float* Wk2 = (const float*)d_in[16]; const float* bk2 = (const float*)d_in[17];
    const float* Wv2 = (const float*)d_in[18]; const float* bv2 = (const float*)d_in[19];
    const float* We2 = (const float*)d_in[20];
    const float* Ws2 = (const float*)d_in[21]; const float* bs2 = (const float*)d_in[22];
    const float* lnw2 = (const float*)d_in[23]; const float* lnb2 = (const float*)d_in[24];
    const float* Wo  = (const float*)d_in[25]; const float* bo  = (const float*)d_in[26];

    const int N = in_sizes[0] / IN_DIM;
    const int E = in_sizes[2];
    const int* esrc = ei;
    const int* edst = ei + E;

    char* ws = (char*)d_ws;
    size_t off = 0;
    auto alloc = [&](size_t bytes) -> char* {
        char* p = ws + off;
        off += (bytes + 255) / 256 * 256;
        return p;
    };
    int*    counts = (int*)alloc((size_t)N * 4);
    int*    cursor = (int*)alloc((size_t)N * 4);
    double* stats  = (double*)alloc(64);
    float*  lnp    = (float*)alloc(256);
    size_t zbytes = off;
    int*    offs   = (int*)alloc((size_t)(N + 1) * 4);
    int2*   edat   = (int2*)alloc((size_t)E * 8);
    __half* xh     = (__half*)alloc((size_t)N * IN_DIM * 2);
    __half* qkvs   = (__half*)alloc((size_t)N * 1024 * 2);
    float*  hwork  = (float*)alloc((size_t)N * HD * 4);
    __half* hio    = (__half*)alloc((size_t)N * HD * 2);
    __half* Wc1    = (__half*)alloc((size_t)1024 * IN_DIM * 2);
    __half* Wc2    = (__half*)alloc((size_t)1024 * HD * 2);
    __half* Wot    = (__half*)alloc((size_t)64 * HD * 2);
    float*  bc1    = (float*)alloc(1024 * 4);
    float*  bc2    = (float*)alloc(1024 * 4);

    hipMemsetAsync(d_ws, 0, zbytes, stream);

    pack_x_k<<<(N * 32 + 255) / 256, 256, 0, stream>>>((const float4*)x, xh, N * 32);
    pack_wcat_k<<<(1024 * IN_DIM + 255) / 256, 256, 0, stream>>>(Wq1, Wk1, Wv1, Ws1, Wc1, IN_DIM);
    pack_wcat_k<<<(1024 * HD + 255) / 256, 256, 0, stream>>>(Wq2, Wk2, Wv2, Ws2, Wc2, HD);
    pack_bcat_k<<<4, 256, 0, stream>>>(bq1, bk1, bv1, bs1, bc1);
    pack_bcat_k<<<4, 256, 0, stream>>>(bq2, bk2, bv2, bs2, bc2);
    pack_wo_k<<<(64 * HD + 255) / 256, 256, 0, stream>>>(Wo, Wot);

    count_k<<<(E + 255) / 256, 256, 0, stream>>>(edst, counts, E);
    scan_k<<<1, 1024, 0, stream>>>(counts, offs, N);
    scatter_k<<<(E + 255) / 256, 256, 0, stream>>>(esrc, edst, eattr, offs, cursor,
                                                   edat, E);

    dim3 gqkvs((N + BM - 1) / BM, 1024 / BN);
    dim3 gout((N + BM - 1) / BM, 1);
    int nGroups = (N + 3) / 4;
    int gaBlocks = nGroups < 2048 ? nGroups : 2048;
    int total4 = N * (HD / 4);
    dim3 gl((total4 + 255) / 256);

    // ---- layer 1 ----
    gemm_mfma<__half><<<gqkvs, 256, 0, stream>>>(xh, Wc1, bc1, qkvs, N, IN_DIM, 1024);
    attn_k<<<gaBlocks, 256, 0, stream>>>((const uint2*)qkvs, (const uint4*)qkvs, We1,
                                         hwork, edat, offs, stats, N, nGroups);
    ln_fin<<<1, 64, 0, stream>>>(stats, lnp, 0, (double)N * HD);
    ln_apply<<<gl, 256, 0, stream>>>((const float4*)hwork, hio,
                                     (const float4*)lnw1, (const float4*)lnb1,
                                     lnp, 0, total4);

    // ---- layer 2 ----
    gemm_mfma<__half><<<gqkvs, 256, 0, stream>>>(hio, Wc2, bc2, qkvs, N, HD, 1024);
    attn_k<<<gaBlocks, 256, 0, stream>>>((const uint2*)qkvs, (const uint4*)qkvs, We2,
                                         hwork, edat, offs, stats + 2, N, nGroups);
    ln_fin<<<1, 64, 0, stream>>>(stats, lnp, 1, (double)N * HD);
    ln_apply<<<gl, 256, 0, stream>>>((const float4*)hwork, hio,
                                     (const float4*)lnw2, (const float4*)lnb2,
                                     lnp, 1, total4);

    // ---- output projection (fp32 out) ----
    gemm_mfma<float><<<gout, 256, 0, stream>>>(hio, Wot, bo, (float*)d_out, N, HD, 64);
}

// Round 8
// 744.734 us; speedup vs baseline: 2.3490x; 1.0093x over previous
//
#include <hip/hip_runtime.h>
#include <hip/hip_fp16.h>
#include <math.h>

#define IN_DIM 128
#define HD 256
#define EPSLN 1e-5f

typedef _Float16 half8 __attribute__((ext_vector_type(8)));
typedef _Float16 h2 __attribute__((ext_vector_type(2)));
typedef float f32x4 __attribute__((ext_vector_type(4)));

// ---------------- helpers ----------------
__device__ inline void store4(float* p, float4 o) { *(float4*)p = o; }
__device__ inline void store4(__half* p, float4 o) {
    union { uint2 u; __half2 h[2]; } s;
    s.h[0] = __floats2half2_rn(o.x, o.y);
    s.h[1] = __floats2half2_rn(o.z, o.w);
    *(uint2*)p = s.u;
}
__device__ inline float4 h4_to_f4(uint2 u) {
    union { unsigned int w; __half2 h; } a, b;
    a.w = u.x; b.w = u.y;
    float2 lo = __half22float2(a.h), hi = __half22float2(b.h);
    return make_float4(lo.x, lo.y, hi.x, hi.y);
}
__device__ inline h2 u2h2(unsigned int u) { union { unsigned int x; h2 h; } c; c.x = u; return c.h; }

__device__ inline void async_copy16(const __half* g, _Float16* l) {
    __builtin_amdgcn_global_load_lds(
        (const __attribute__((address_space(1))) void*)g,
        (__attribute__((address_space(3))) void*)l,
        16, 0, 0);
}

// Packed output column mapping: q[0:256) | kv-interleaved[256:768) | skip[768:1024)
__device__ inline void unpermute_col(int n, int& sel, int& c) {
    if (n < 256) { sel = 0; c = n; }
    else if (n < 768) {
        int j = n - 256, chunk = j >> 3, w = j & 7;
        if (w < 4) { sel = 1; c = chunk * 4 + w; }
        else       { sel = 2; c = chunk * 4 + w - 4; }
    } else { sel = 3; c = n - 768; }
}

// ---------------- pack kernels ----------------
__global__ void pack_x_k(const float4* __restrict__ x, __half* __restrict__ xh, int total4)
{
    int i = blockIdx.x * 256 + threadIdx.x;
    if (i < total4) store4(xh + (size_t)i * 4, x[i]);
}

// one kernel for all weight/bias packing:
// [0, 131072)            Wc1[n][k], K=128
// [131072, 393216)       Wc2[n][k], K=256
// [393216, 409600)       Wot[n][k], 64x256
// [409600, 410624)       bc1
// [410624, 411648)       bc2
__global__ void pack_all_k(
    const float* __restrict__ Wq1, const float* __restrict__ Wk1,
    const float* __restrict__ Wv1, const float* __restrict__ Ws1,
    const float* __restrict__ Wq2, const float* __restrict__ Wk2,
    const float* __restrict__ Wv2, const float* __restrict__ Ws2,
    const float* __restrict__ Wo,
    const float* __restrict__ bq1, const float* __restrict__ bk1,
    const float* __restrict__ bv1, const float* __restrict__ bs1,
    const float* __restrict__ bq2, const float* __restrict__ bk2,
    const float* __restrict__ bv2, const float* __restrict__ bs2,
    __half* __restrict__ Wc1, __half* __restrict__ Wc2, __half* __restrict__ Wot,
    float* __restrict__ bc1, float* __restrict__ bc2)
{
    int idx = blockIdx.x * 256 + threadIdx.x;
    if (idx < 131072) {
        int n = idx >> 7, k = idx & 127;
        int sel, c; unpermute_col(n, sel, c);
        const float* W = (sel == 0) ? Wq1 : (sel == 1) ? Wk1 : (sel == 2) ? Wv1 : Ws1;
        Wc1[idx] = __float2half(W[(size_t)k * 256 + c]);
    } else if (idx < 393216) {
        int j = idx - 131072;
        int n = j >> 8, k = j & 255;
        int sel, c; unpermute_col(n, sel, c);
        const float* W = (sel == 0) ? Wq2 : (sel == 1) ? Wk2 : (sel == 2) ? Wv2 : Ws2;
        Wc2[j] = __float2half(W[(size_t)k * 256 + c]);
    } else if (idx < 409600) {
        int j = idx - 393216;
        int n = j >> 8, k = j & 255;
        Wot[j] = __float2half(Wo[(size_t)k * 64 + n]);
    } else if (idx < 410624) {
        int n = idx - 409600;
        int sel, c; unpermute_col(n, sel, c);
        const float* b = (sel == 0) ? bq1 : (sel == 1) ? bk1 : (sel == 2) ? bv1 : bs1;
        bc1[n] = b[c];
    } else if (idx < 411648) {
        int n = idx - 410624;
        int sel, c; unpermute_col(n, sel, c);
        const float* b = (sel == 0) ? bq2 : (sel == 1) ? bk2 : (sel == 2) ? bv2 : bs2;
        bc2[n] = b[c];
    }
}

// ---------------- MFMA GEMM: C[M x Nc] = A[M x K] @ Wt^T + bias ----------------
// global_load_lds staging (width 16), BK=64, XOR-swizzled LDS chunks.
#define BM 128
#define BN 128
#define BK 64
#define TROWB 272   // f16 out-tile row stride (bytes)

template <typename OT>
__global__ __launch_bounds__(256) void gemm_mfma(
    const __half* __restrict__ A, const __half* __restrict__ Wt,
    const float* __restrict__ bias, OT* __restrict__ C,
    int M, int K, int Nc)
{
    __shared__ char smem[BM * TROWB];          // 34 KB; As|Bs in K-loop (32 KB), out-tile after
    _Float16* As = (_Float16*)smem;            // [128][64] halves, row = 128 B
    _Float16* Bs = (_Float16*)(smem + 16384);

    int tid = threadIdx.x;
    int lane = tid & 63, w = tid >> 6;
    int wm = w >> 1, wn = w & 1;
    int quad = lane >> 4, l16 = lane & 15;
    int row0 = blockIdx.x * BM, col0 = blockIdx.y * BN;

    f32x4 acc[4][4];
#pragma unroll
    for (int i = 0; i < 4; i++)
#pragma unroll
        for (int j = 0; j < 4; j++) acc[i][j] = (f32x4){0.f, 0.f, 0.f, 0.f};

    int srow = lane >> 3;    // row within 8-row group
    int schunk = lane & 7;   // 16B chunk within row

    for (int k0 = 0; k0 < K; k0 += BK) {
        // stage A: 4 waves x 4 insts x (8 rows x 128B) = 128 rows
#pragma unroll
        for (int t = 0; t < 4; t++) {
            int r = w * 32 + t * 8 + srow;
            int gr = row0 + r; if (gr > M - 1) gr = M - 1;
            int gchunk = schunk ^ (r & 7);                  // swizzle folded into global side
            async_copy16(&A[(size_t)gr * K + k0 + gchunk * 8], &As[(w * 32 + t * 8) * 64]);
        }
#pragma unroll
        for (int t = 0; t < 4; t++) {
            int r = w * 32 + t * 8 + srow;
            int gc = col0 + r; if (gc > Nc - 1) gc = Nc - 1;
            int gchunk = schunk ^ (r & 7);
            async_copy16(&Wt[(size_t)gc * K + k0 + gchunk * 8], &Bs[(w * 32 + t * 8) * 64]);
        }
        __syncthreads();

#pragma unroll
        for (int ks = 0; ks < 2; ks++) {
            half8 af[4], bf[4];
#pragma unroll
            for (int i = 0; i < 4; i++) {
                int ra = wm * 64 + i * 16 + l16;
                af[i] = *(half8*)&As[ra * 64 + (((ks * 4 + quad) ^ (ra & 7)) * 8)];
                int rb = wn * 64 + i * 16 + l16;
                bf[i] = *(half8*)&Bs[rb * 64 + (((ks * 4 + quad) ^ (rb & 7)) * 8)];
            }
#pragma unroll
            for (int i = 0; i < 4; i++)
#pragma unroll
                for (int j = 0; j < 4; j++)
                    acc[i][j] = __builtin_amdgcn_mfma_f32_16x16x32_f16(af[i], bf[j], acc[i][j], 0, 0, 0);
        }
        __syncthreads();
    }

    if constexpr (sizeof(OT) == 2) {
        // f16: stage tile in LDS, coalesced 16B copy-out
#pragma unroll
        for (int j = 0; j < 4; j++) {
            int tcol = wn * 64 + j * 16 + l16;
            float bb = (col0 + tcol < Nc) ? bias[col0 + tcol] : 0.f;
#pragma unroll
            for (int i = 0; i < 4; i++) {
#pragma unroll
                for (int r = 0; r < 4; r++) {
                    int trow = wm * 64 + i * 16 + quad * 4 + r;
                    ((__half*)(smem + trow * TROWB))[tcol] = __float2half(acc[i][j][r] + bb);
                }
            }
        }
        __syncthreads();
        int crow = tid >> 4, cchunk = tid & 15;
        for (int p = 0; p < 8; p++) {
            int trow = p * 16 + crow;
            int grow = row0 + trow;
            int gcol = cchunk * 8;
            if (grow < M && col0 + gcol < Nc) {
                uint4 val = *(uint4*)(smem + trow * TROWB + cchunk * 16);
                *(uint4*)&((__half*)C)[(size_t)grow * Nc + col0 + gcol] = val;
            }
        }
    } else {
        // fp32 (small output GEMM): direct stores
#pragma unroll
        for (int i = 0; i < 4; i++) {
#pragma unroll
            for (int j = 0; j < 4; j++) {
                int gcol = col0 + wn * 64 + j * 16 + l16;
                if (gcol >= Nc) continue;
                float bb = bias[gcol];
#pragma unroll
                for (int r = 0; r < 4; r++) {
                    int grow = row0 + wm * 64 + i * 16 + quad * 4 + r;
                    if (grow < M) ((float*)C)[(size_t)grow * Nc + gcol] = acc[i][j][r] + bb;
                }
            }
        }
    }
}

// ---------------- edge bucketing (counting sort by dst) ----------------
__global__ void count_k(const int* __restrict__ dst, int* __restrict__ counts, int E)
{
    int e = blockIdx.x * 256 + threadIdx.x;
    if (e < E) atomicAdd(&counts[dst[e]], 1);
}

__global__ __launch_bounds__(1024) void scan_k(const int* __restrict__ counts,
                                               int* __restrict__ offs, int n)
{
    __shared__ int wsum[16];
    __shared__ int wpre[16];
    int tid = threadIdx.x, lane = tid & 63, wid = tid >> 6;
    int per = (n + 1023) / 1024;
    int start = tid * per, end = min(start + per, n);
    int sum = 0;
    for (int i = start; i < end; i++) sum += counts[i];
    int v = sum;
#pragma unroll
    for (int d = 1; d < 64; d <<= 1) {
        int t = __shfl_up(v, (unsigned)d, 64);
        if (lane >= d) v += t;
    }
    if (lane == 63) wsum[wid] = v;
    __syncthreads();
    if (tid == 0) {
        int acc = 0;
        for (int i = 0; i < 16; i++) { wpre[i] = acc; acc += wsum[i]; }
    }
    __syncthreads();
    int pre = wpre[wid] + v - sum;
    for (int i = start; i < end; i++) { offs[i] = pre; pre += counts[i]; }
    if (end == n && start <= n) offs[n] = pre;
}

__global__ void scatter_k(const int* __restrict__ src, const int* __restrict__ dst,
                          const float* __restrict__ attr, const int* __restrict__ offs,
                          int* __restrict__ cursor, int2* __restrict__ edat, int E)
{
    int e = blockIdx.x * 256 + threadIdx.x;
    if (e < E) {
        int d = dst[e];
        int p = offs[d] + atomicAdd(&cursor[d], 1);
        edat[p] = make_int2(src[e], __float_as_int(attr[e]));
    }
}

// ---------------- attention: one wave per dst node, online softmax ----------------
__global__ __launch_bounds__(256) void attn_k(
    const uint2* __restrict__ q2, const uint4* __restrict__ kv4,
    const float* __restrict__ We,
    float* __restrict__ hwork, const int2* __restrict__ edat,
    const int* __restrict__ offs,
    double* __restrict__ stats, int n, int nGroups)
{
    int lane = threadIdx.x & 63;
    int wid = threadIdx.x >> 6;
    float4 we = ((const float4*)We)[lane];
    float tsum = 0.f, tsq = 0.f;

    for (int g = blockIdx.x; g < nGroups; g += gridDim.x) {
        int node = g * 4 + wid;
        if (node >= n) continue;
        uint2 qraw = q2[(size_t)node * 256 + lane];
        h2 q01 = u2h2(qraw.x), q23 = u2h2(qraw.y);
        float4 qv = h4_to_f4(qraw);
        float qwe = qv.x * we.x + qv.y * we.y + qv.z * we.z + qv.w * we.w;
        qwe += __shfl_xor(qwe, 1);
        qwe += __shfl_xor(qwe, 2);
        qwe += __shfl_xor(qwe, 4);

        float4 accv = make_float4(0.f, 0.f, 0.f, 0.f);
        float sat = 0.f;
        float m = -INFINITY, l = 0.f;
        int i0 = offs[node], i1 = offs[node + 1];

        auto proc = [&](uint4 kvraw, float at) {
            float p = __builtin_amdgcn_fdot2(u2h2(kvraw.x), q01,
                      __builtin_amdgcn_fdot2(u2h2(kvraw.y), q23, 0.f, false), false);
            p += __shfl_xor(p, 1);
            p += __shfl_xor(p, 2);
            p += __shfl_xor(p, 4);
            p = fmaf(at, qwe, p) * 0.17677669529663687f;   // (q.k + at*q.we)/sqrt(32)
            float mn = fmaxf(m, p);
            float corr = __expf(m - mn);
            float wgt = __expf(p - mn);
            l = l * corr + wgt;
            sat = fmaf(sat, corr, wgt * at);
            float4 vv = h4_to_f4(make_uint2(kvraw.z, kvraw.w));
            accv.x = fmaf(accv.x, corr, wgt * vv.x);
            accv.y = fmaf(accv.y, corr, wgt * vv.y);
            accv.z = fmaf(accv.z, corr, wgt * vv.z);
            accv.w = fmaf(accv.w, corr, wgt * vv.w);
            m = mn;
        };

        int i = i0;
        for (; i + 8 <= i1; i += 8) {
            int2 ed[8];
#pragma unroll
            for (int u = 0; u < 8; u++) ed[u] = edat[i + u];
            uint4 kvv[8];
#pragma unroll
            for (int u = 0; u < 8; u++)
                kvv[u] = kv4[(size_t)ed[u].x * 128 + 32 + lane];
#pragma unroll
            for (int u = 0; u < 8; u++) proc(kvv[u], __int_as_float(ed[u].y));
        }
        for (; i < i1; i++) {
            int2 ed = edat[i];
            uint4 kvraw = kv4[(size_t)ed.x * 128 + 32 + lane];
            proc(kvraw, __int_as_float(ed.y));
        }

        float inv = (l > 0.f) ? 1.f / l : 0.f;
        float4 sk = h4_to_f4(q2[(size_t)node * 256 + 192 + lane]);
        float sw = sat * inv;
        float4 o;
        o.x = fmaf(accv.x, inv, fmaf(sw, we.x, sk.x));
        o.y = fmaf(accv.y, inv, fmaf(sw, we.y, sk.y));
        o.z = fmaf(accv.z, inv, fmaf(sw, we.z, sk.z));
        o.w = fmaf(accv.w, inv, fmaf(sw, we.w, sk.w));
        ((float4*)hwork)[(size_t)node * 64 + lane] = o;
        tsum += o.x + o.y + o.z + o.w;
        tsq += o.x * o.x + o.y * o.y + o.z * o.z + o.w * o.w;
    }

#pragma unroll
    for (int d = 1; d < 64; d <<= 1) {
        tsum += __shfl_xor(tsum, d);
        tsq += __shfl_xor(tsq, d);
    }
    __shared__ float red[8];
    if (lane == 0) { red[wid] = tsum; red[4 + wid] = tsq; }
    __syncthreads();
    if (threadIdx.x == 0) {
        double s = (double)red[0] + (double)red[1] + (double)red[2] + (double)red[3];
        double sq = (double)red[4] + (double)red[5] + (double)red[6] + (double)red[7];
        atomicAdd(&stats[0], s);
        atomicAdd(&stats[1], sq);
    }
}

// ---------------- LayerNorm apply (stats finalize fused per block) ----------------
__global__ __launch_bounds__(256) void ln_apply(
    const float4* __restrict__ in, __half* __restrict__ out,
    const float4* __restrict__ w4, const float4* __restrict__ b4,
    const double* __restrict__ stats, double cnt, int total4)
{
    int i = blockIdx.x * 256 + threadIdx.x;
    if (i >= total4) return;
    double mu = stats[0] / cnt;
    double var = stats[1] / cnt - mu * mu;
    if (var < 0.0) var = 0.0;
    float mean = (float)mu;
    float inv = (float)(1.0 / (sqrt(var) + (double)EPSLN));
    int c = i & 63;
    float4 xv = in[i], w = w4[c], b = b4[c];
    float4 o;
    o.x = fmaf((xv.x - mean) * inv, w.x, b.x);
    o.y = fmaf((xv.y - mean) * inv, w.y, b.y);
    o.z = fmaf((xv.z - mean) * inv, w.z, b.z);
    o.w = fmaf((xv.w - mean) * inv, w.w, b.w);
    o.x = o.x > 0.f ? o.x : expm1f(o.x);
    o.y = o.y > 0.f ? o.y : expm1f(o.y);
    o.z = o.z > 0.f ? o.z : expm1f(o.z);
    o.w = o.w > 0.f ? o.w : expm1f(o.w);
    store4(out + (size_t)i * 4, o);
}

// ---------------- driver ----------------
extern "C" void kernel_launch(void* const* d_in, const int* in_sizes, int n_in,
                              void* d_out, int out_size, void* d_ws, size_t ws_size,
                              hipStream_t stream)
{
    const float* x      = (const float*)d_in[0];
    const int*   ei     = (const int*)d_in[1];
    const float* eattr  = (const float*)d_in[2];
    const float* Wq1 = (const float*)d_in[3];  const float* bq1 = (const float*)d_in[4];
    const float* Wk1 = (const float*)d_in[5];  const float* bk1 = (const float*)d_in[6];
    const float* Wv1 = (const float*)d_in[7];  const float* bv1 = (const float*)d_in[8];
    const float* We1 = (const float*)d_in[9];
    const float* Ws1 = (const float*)d_in[10]; const float* bs1 = (const float*)d_in[11];
    const float* lnw1 = (const float*)d_in[12]; const float* lnb1 = (const float*)d_in[13];
    const float* Wq2 = (const float*)d_in[14]; const float* bq2 = (const float*)d_in[15];
    const float* Wk2 = (const float*)d_in[16]; const float* bk2 = (const float*)d_in[17];
    const float* Wv2 = (const float*)d_in[18]; const float* bv2 = (const float*)d_in[19];
    const float* We2 = (const float*)d_in[20];
    const float* Ws2 = (const float*)d_in[21]; const float* bs2 = (const float*)d_in[22];
    const float* lnw2 = (const float*)d_in[23]; const float* lnb2 = (const float*)d_in[24];
    const float* Wo  = (const float*)d_in[25]; const float* bo  = (const float*)d_in[26];

    const int N = in_sizes[0] / IN_DIM;
    const int E = in_sizes[2];
    const int* esrc = ei;
    const int* edst = ei + E;

    char* ws = (char*)d_ws;
    size_t off = 0;
    auto alloc = [&](size_t bytes) -> char* {
        char* p = ws + off;
        off += (bytes + 255) / 256 * 256;
        return p;
    };
    int*    counts = (int*)alloc((size_t)N * 4);
    int*    cursor = (int*)alloc((size_t)N * 4);
    double* stats  = (double*)alloc(64);
    size_t zbytes = off;
    int*    offs   = (int*)alloc((size_t)(N + 1) * 4);
    int2*   edat   = (int2*)alloc((size_t)E * 8);
    __half* xh     = (__half*)alloc((size_t)N * IN_DIM * 2);
    __half* qkvs   = (__half*)alloc((size_t)N * 1024 * 2);
    float*  hwork  = (float*)alloc((size_t)N * HD * 4);
    __half* hio    = (__half*)alloc((size_t)N * HD * 2);
    __half* Wc1    = (__half*)alloc((size_t)1024 * IN_DIM * 2);
    __half* Wc2    = (__half*)alloc((size_t)1024 * HD * 2);
    __half* Wot    = (__half*)alloc((size_t)64 * HD * 2);
    float*  bc1    = (float*)alloc(1024 * 4);
    float*  bc2    = (float*)alloc(1024 * 4);

    hipMemsetAsync(d_ws, 0, zbytes, stream);

    pack_x_k<<<(N * 32 + 255) / 256, 256, 0, stream>>>((const float4*)x, xh, N * 32);
    pack_all_k<<<(411648 + 255) / 256, 256, 0, stream>>>(
        Wq1, Wk1, Wv1, Ws1, Wq2, Wk2, Wv2, Ws2, Wo,
        bq1, bk1, bv1, bs1, bq2, bk2, bv2, bs2,
        Wc1, Wc2, Wot, bc1, bc2);

    count_k<<<(E + 255) / 256, 256, 0, stream>>>(edst, counts, E);
    scan_k<<<1, 1024, 0, stream>>>(counts, offs, N);
    scatter_k<<<(E + 255) / 256, 256, 0, stream>>>(esrc, edst, eattr, offs, cursor,
                                                   edat, E);

    dim3 gqkvs((N + BM - 1) / BM, 1024 / BN);
    dim3 gout((N + BM - 1) / BM, 1);
    int nGroups = (N + 3) / 4;
    int gaBlocks = nGroups < 2048 ? nGroups : 2048;
    int total4 = N * (HD / 4);
    dim3 gl((total4 + 255) / 256);

    // ---- layer 1 ----
    gemm_mfma<__half><<<gqkvs, 256, 0, stream>>>(xh, Wc1, bc1, qkvs, N, IN_DIM, 1024);
    attn_k<<<gaBlocks, 256, 0, stream>>>((const uint2*)qkvs, (const uint4*)qkvs, We1,
                                         hwork, edat, offs, stats, N, nGroups);
    ln_apply<<<gl, 256, 0, stream>>>((const float4*)hwork, hio,
                                     (const float4*)lnw1, (const float4*)lnb1,
                                     stats, (double)N * HD, total4);

    // ---- layer 2 ----
    gemm_mfma<__half><<<gqkvs, 256, 0, stream>>>(hio, Wc2, bc2, qkvs, N, HD, 1024);
    attn_k<<<gaBlocks, 256, 0, stream>>>((const uint2*)qkvs, (const uint4*)qkvs, We2,
                                         hwork, edat, offs, stats + 2, N, nGroups);
    ln_apply<<<gl, 256, 0, stream>>>((const float4*)hwork, hio,
                                     (const float4*)lnw2, (const float4*)lnb2,
                                     stats + 2, (double)N * HD, total4);

    // ---- output projection (fp32 out) ----
    gemm_mfma<float><<<gout, 256, 0, stream>>>(hio, Wot, bo, (float*)d_out, N, HD, 64);
}

// Round 9
// 664.037 us; speedup vs baseline: 2.6345x; 1.1215x over previous
//
#include <hip/hip_runtime.h>
#include <hip/hip_fp16.h>
#include <math.h>

#define IN_DIM 128
#define HD 256
#define EPSLN 1e-5f

typedef _Float16 half8 __attribute__((ext_vector_type(8)));
typedef float f32x4 __attribute__((ext_vector_type(4)));
typedef float f32x2 __attribute__((ext_vector_type(2)));

// ---------------- helpers ----------------
__device__ inline void store4(float* p, float4 o) { *(float4*)p = o; }
__device__ inline void store4(__half* p, float4 o) {
    union { uint2 u; __half2 h[2]; } s;
    s.h[0] = __floats2half2_rn(o.x, o.y);
    s.h[1] = __floats2half2_rn(o.z, o.w);
    *(uint2*)p = s.u;
}
__device__ inline float4 h4_to_f4(uint2 u) {
    union { unsigned int w; __half2 h; } a, b;
    a.w = u.x; b.w = u.y;
    float2 lo = __half22float2(a.h), hi = __half22float2(b.h);
    return make_float4(lo.x, lo.y, hi.x, hi.y);
}
// 4 floats -> 4 packed fp8 e4m3 (OCP, gfx950 HW cvt)
__device__ inline unsigned int f4_to_fp8x4(float a, float b, float c, float d) {
    int v = 0;
    v = __builtin_amdgcn_cvt_pk_fp8_f32(a, b, v, false);
    v = __builtin_amdgcn_cvt_pk_fp8_f32(c, d, v, true);
    return (unsigned int)v;
}
__device__ inline float4 fp8x4_to_f4(unsigned int u) {
    f32x2 lo = __builtin_amdgcn_cvt_pk_f32_fp8((int)u, false);
    f32x2 hi = __builtin_amdgcn_cvt_pk_f32_fp8((int)u, true);
    return make_float4(lo.x, lo.y, hi.x, hi.y);
}

__device__ inline void async_copy16(const __half* g, _Float16* l) {
    __builtin_amdgcn_global_load_lds(
        (const __attribute__((address_space(1))) void*)g,
        (__attribute__((address_space(3))) void*)l,
        16, 0, 0);
}

// Packed output column mapping: q[0:256) | kv-interleaved[256:768) | skip[768:1024)
__device__ inline void unpermute_col(int n, int& sel, int& c) {
    if (n < 256) { sel = 0; c = n; }
    else if (n < 768) {
        int j = n - 256, chunk = j >> 3, w = j & 7;
        if (w < 4) { sel = 1; c = chunk * 4 + w; }
        else       { sel = 2; c = chunk * 4 + w - 4; }
    } else { sel = 3; c = n - 768; }
}

// ---------------- fused prep: pack x -> f16, pack weights/biases, count degrees ----
__global__ void prep_k(
    const float4* __restrict__ x, __half* __restrict__ xh, int total4,
    const int* __restrict__ dst, int* __restrict__ counts, int E,
    const float* __restrict__ Wq1, const float* __restrict__ Wk1,
    const float* __restrict__ Wv1, const float* __restrict__ Ws1,
    const float* __restrict__ Wq2, const float* __restrict__ Wk2,
    const float* __restrict__ Wv2, const float* __restrict__ Ws2,
    const float* __restrict__ Wo,
    const float* __restrict__ bq1, const float* __restrict__ bk1,
    const float* __restrict__ bv1, const float* __restrict__ bs1,
    const float* __restrict__ bq2, const float* __restrict__ bk2,
    const float* __restrict__ bv2, const float* __restrict__ bs2,
    __half* __restrict__ Wc1, __half* __restrict__ Wc2, __half* __restrict__ Wot,
    float* __restrict__ bc1, float* __restrict__ bc2)
{
    int idx = blockIdx.x * 256 + threadIdx.x;
    if (idx < total4) store4(xh + (size_t)idx * 4, x[idx]);
    if (idx < E) atomicAdd(&counts[dst[idx]], 1);
    if (idx < 131072) {
        int n = idx >> 7, k = idx & 127;
        int sel, c; unpermute_col(n, sel, c);
        const float* W = (sel == 0) ? Wq1 : (sel == 1) ? Wk1 : (sel == 2) ? Wv1 : Ws1;
        Wc1[idx] = __float2half(W[(size_t)k * 256 + c]);
    } else if (idx < 393216) {
        int j = idx - 131072;
        int n = j >> 8, k = j & 255;
        int sel, c; unpermute_col(n, sel, c);
        const float* W = (sel == 0) ? Wq2 : (sel == 1) ? Wk2 : (sel == 2) ? Wv2 : Ws2;
        Wc2[j] = __float2half(W[(size_t)k * 256 + c]);
    } else if (idx < 409600) {
        int j = idx - 393216;
        int n = j >> 8, k = j & 255;
        Wot[j] = __float2half(Wo[(size_t)k * 64 + n]);
    } else if (idx < 410624) {
        int n = idx - 409600;
        int sel, c; unpermute_col(n, sel, c);
        const float* b = (sel == 0) ? bq1 : (sel == 1) ? bk1 : (sel == 2) ? bv1 : bs1;
        bc1[n] = b[c];
    } else if (idx < 411648) {
        int n = idx - 410624;
        int sel, c; unpermute_col(n, sel, c);
        const float* b = (sel == 0) ? bq2 : (sel == 1) ? bk2 : (sel == 2) ? bv2 : bs2;
        bc2[n] = b[c];
    }
}

// ---------------- MFMA GEMM: C[M x Nc] = A[M x K] @ Wt^T + bias ----------------
// global_load_lds staging (width 16), BK=64, XOR-swizzled LDS chunks.
// f16 path: kv column tiles [256,768) are emitted as fp8 into kv8 (f16 copy skipped).
#define BM 128
#define BN 128
#define BK 64
#define TROWB 272   // f16 out-tile row stride (bytes)

template <typename OT>
__global__ __launch_bounds__(256) void gemm_mfma(
    const __half* __restrict__ A, const __half* __restrict__ Wt,
    const float* __restrict__ bias, OT* __restrict__ C,
    unsigned char* __restrict__ kv8,
    int M, int K, int Nc)
{
    __shared__ char smem[BM * TROWB];          // 34 KB; As|Bs in K-loop (32 KB), out-tile after
    _Float16* As = (_Float16*)smem;            // [128][64] halves, row = 128 B
    _Float16* Bs = (_Float16*)(smem + 16384);

    int tid = threadIdx.x;
    int lane = tid & 63, w = tid >> 6;
    int wm = w >> 1, wn = w & 1;
    int quad = lane >> 4, l16 = lane & 15;
    int row0 = blockIdx.x * BM, col0 = blockIdx.y * BN;

    f32x4 acc[4][4];
#pragma unroll
    for (int i = 0; i < 4; i++)
#pragma unroll
        for (int j = 0; j < 4; j++) acc[i][j] = (f32x4){0.f, 0.f, 0.f, 0.f};

    int srow = lane >> 3;    // row within 8-row group
    int schunk = lane & 7;   // 16B chunk within row

    for (int k0 = 0; k0 < K; k0 += BK) {
#pragma unroll
        for (int t = 0; t < 4; t++) {
            int r = w * 32 + t * 8 + srow;
            int gr = row0 + r; if (gr > M - 1) gr = M - 1;
            int gchunk = schunk ^ (r & 7);                  // swizzle folded into global side
            async_copy16(&A[(size_t)gr * K + k0 + gchunk * 8], &As[(w * 32 + t * 8) * 64]);
        }
#pragma unroll
        for (int t = 0; t < 4; t++) {
            int r = w * 32 + t * 8 + srow;
            int gc = col0 + r; if (gc > Nc - 1) gc = Nc - 1;
            int gchunk = schunk ^ (r & 7);
            async_copy16(&Wt[(size_t)gc * K + k0 + gchunk * 8], &Bs[(w * 32 + t * 8) * 64]);
        }
        __syncthreads();

#pragma unroll
        for (int ks = 0; ks < 2; ks++) {
            half8 af[4], bf[4];
#pragma unroll
            for (int i = 0; i < 4; i++) {
                int ra = wm * 64 + i * 16 + l16;
                af[i] = *(half8*)&As[ra * 64 + (((ks * 4 + quad) ^ (ra & 7)) * 8)];
                int rb = wn * 64 + i * 16 + l16;
                bf[i] = *(half8*)&Bs[rb * 64 + (((ks * 4 + quad) ^ (rb & 7)) * 8)];
            }
#pragma unroll
            for (int i = 0; i < 4; i++)
#pragma unroll
                for (int j = 0; j < 4; j++)
                    acc[i][j] = __builtin_amdgcn_mfma_f32_16x16x32_f16(af[i], bf[j], acc[i][j], 0, 0, 0);
        }
        __syncthreads();
    }

    if constexpr (sizeof(OT) == 2) {
        // stage tile in LDS as f16
#pragma unroll
        for (int j = 0; j < 4; j++) {
            int tcol = wn * 64 + j * 16 + l16;
            float bb = (col0 + tcol < Nc) ? bias[col0 + tcol] : 0.f;
#pragma unroll
            for (int i = 0; i < 4; i++) {
#pragma unroll
                for (int r = 0; r < 4; r++) {
                    int trow = wm * 64 + i * 16 + quad * 4 + r;
                    ((__half*)(smem + trow * TROWB))[tcol] = __float2half(acc[i][j][r] + bb);
                }
            }
        }
        __syncthreads();
        bool iskv = (col0 >= 256) && (col0 < 768);
        int crow = tid >> 4, cchunk = tid & 15;
        for (int p = 0; p < 8; p++) {
            int trow = p * 16 + crow;
            int grow = row0 + trow;
            if (grow >= M) continue;
            uint4 val = *(uint4*)(smem + trow * TROWB + cchunk * 16);
            if (iskv) {
                // convert 8 halves -> 8 fp8, store to kv8[grow][col0-256 + cchunk*8]
                float4 lo = h4_to_f4(make_uint2(val.x, val.y));
                float4 hi = h4_to_f4(make_uint2(val.z, val.w));
                uint2 o8;
                o8.x = f4_to_fp8x4(lo.x, lo.y, lo.z, lo.w);
                o8.y = f4_to_fp8x4(hi.x, hi.y, hi.z, hi.w);
                *(uint2*)&kv8[(size_t)grow * 512 + (col0 - 256) + cchunk * 8] = o8;
            } else {
                *(uint4*)&((__half*)C)[(size_t)grow * Nc + col0 + cchunk * 8] = val;
            }
        }
    } else {
        // fp32 (small output GEMM): direct stores
#pragma unroll
        for (int i = 0; i < 4; i++) {
#pragma unroll
            for (int j = 0; j < 4; j++) {
                int gcol = col0 + wn * 64 + j * 16 + l16;
                if (gcol >= Nc) continue;
                float bb = bias[gcol];
#pragma unroll
                for (int r = 0; r < 4; r++) {
                    int grow = row0 + wm * 64 + i * 16 + quad * 4 + r;
                    if (grow < M) ((float*)C)[(size_t)grow * Nc + gcol] = acc[i][j][r] + bb;
                }
            }
        }
    }
}

// ---------------- edge bucketing ----------------
__global__ __launch_bounds__(1024) void scan_k(const int* __restrict__ counts,
                                               int* __restrict__ offs, int n)
{
    __shared__ int wsum[16];
    __shared__ int wpre[16];
    int tid = threadIdx.x, lane = tid & 63, wid = tid >> 6;
    int per = (n + 1023) / 1024;
    int start = tid * per, end = min(start + per, n);
    int sum = 0;
    for (int i = start; i < end; i++) sum += counts[i];
    int v = sum;
#pragma unroll
    for (int d = 1; d < 64; d <<= 1) {
        int t = __shfl_up(v, (unsigned)d, 64);
        if (lane >= d) v += t;
    }
    if (lane == 63) wsum[wid] = v;
    __syncthreads();
    if (tid == 0) {
        int acc = 0;
        for (int i = 0; i < 16; i++) { wpre[i] = acc; acc += wsum[i]; }
    }
    __syncthreads();
    int pre = wpre[wid] + v - sum;
    for (int i = start; i < end; i++) { offs[i] = pre; pre += counts[i]; }
    if (end == n && start <= n) offs[n] = pre;
}

__global__ void scatter_k(const int* __restrict__ src, const int* __restrict__ dst,
                          const float* __restrict__ attr, const int* __restrict__ offs,
                          int* __restrict__ cursor, int2* __restrict__ edat, int E)
{
    int e = blockIdx.x * 256 + threadIdx.x;
    if (e < E) {
        int d = dst[e];
        int p = offs[d] + atomicAdd(&cursor[d], 1);
        edat[p] = make_int2(src[e], __float_as_int(attr[e]));
    }
}

// ---------------- attention: one wave per dst node, online softmax ----------------
// q/skip from qkvs f16; k,v from kv8 (fp8 e4m3, interleaved k4|v4 per 8B chunk).
__global__ __launch_bounds__(256) void attn_k(
    const uint2* __restrict__ q2, const uint2* __restrict__ kv8u2,
    const float* __restrict__ We,
    __half* __restrict__ hwork, const int2* __restrict__ edat,
    const int* __restrict__ offs,
    double* __restrict__ stats, int n, int nGroups)
{
    int lane = threadIdx.x & 63;
    int wid = threadIdx.x >> 6;
    float4 we = ((const float4*)We)[lane];
    float tsum = 0.f, tsq = 0.f;

    for (int g = blockIdx.x; g < nGroups; g += gridDim.x) {
        int node = g * 4 + wid;
        if (node >= n) continue;
        float4 qv = h4_to_f4(q2[(size_t)node * 256 + lane]);
        float qwe = qv.x * we.x + qv.y * we.y + qv.z * we.z + qv.w * we.w;
        qwe += __shfl_xor(qwe, 1);
        qwe += __shfl_xor(qwe, 2);
        qwe += __shfl_xor(qwe, 4);

        float4 accv = make_float4(0.f, 0.f, 0.f, 0.f);
        float sat = 0.f;
        float m = -INFINITY, l = 0.f;
        int i0 = offs[node], i1 = offs[node + 1];

        auto proc = [&](uint2 kvraw, float at) {
            float4 kv = fp8x4_to_f4(kvraw.x);
            float p = qv.x * kv.x + qv.y * kv.y + qv.z * kv.z + qv.w * kv.w;
            p += __shfl_xor(p, 1);
            p += __shfl_xor(p, 2);
            p += __shfl_xor(p, 4);
            p = fmaf(at, qwe, p) * 0.17677669529663687f;   // (q.k + at*q.we)/sqrt(32)
            float mn = fmaxf(m, p);
            float corr = __expf(m - mn);
            float wgt = __expf(p - mn);
            l = l * corr + wgt;
            sat = fmaf(sat, corr, wgt * at);
            float4 vv = fp8x4_to_f4(kvraw.y);
            accv.x = fmaf(accv.x, corr, wgt * vv.x);
            accv.y = fmaf(accv.y, corr, wgt * vv.y);
            accv.z = fmaf(accv.z, corr, wgt * vv.z);
            accv.w = fmaf(accv.w, corr, wgt * vv.w);
            m = mn;
        };

        int i = i0;
        for (; i + 8 <= i1; i += 8) {
            int2 ed[8];
#pragma unroll
            for (int u = 0; u < 8; u++) ed[u] = edat[i + u];
            uint2 kvv[8];
#pragma unroll
            for (int u = 0; u < 8; u++)
                kvv[u] = kv8u2[(size_t)ed[u].x * 64 + lane];
#pragma unroll
            for (int u = 0; u < 8; u++) proc(kvv[u], __int_as_float(ed[u].y));
        }
        for (; i < i1; i++) {
            int2 ed = edat[i];
            uint2 kvraw = kv8u2[(size_t)ed.x * 64 + lane];
            proc(kvraw, __int_as_float(ed.y));
        }

        float inv = (l > 0.f) ? 1.f / l : 0.f;
        float4 sk = h4_to_f4(q2[(size_t)node * 256 + 192 + lane]);
        float sw = sat * inv;
        float4 o;
        o.x = fmaf(accv.x, inv, fmaf(sw, we.x, sk.x));
        o.y = fmaf(accv.y, inv, fmaf(sw, we.y, sk.y));
        o.z = fmaf(accv.z, inv, fmaf(sw, we.z, sk.z));
        o.w = fmaf(accv.w, inv, fmaf(sw, we.w, sk.w));
        store4(hwork + (size_t)node * 256 + lane * 4, o);
        tsum += o.x + o.y + o.z + o.w;
        tsq += o.x * o.x + o.y * o.y + o.z * o.z + o.w * o.w;
    }

#pragma unroll
    for (int d = 1; d < 64; d <<= 1) {
        tsum += __shfl_xor(tsum, d);
        tsq += __shfl_xor(tsq, d);
    }
    __shared__ float red[8];
    if (lane == 0) { red[wid] = tsum; red[4 + wid] = tsq; }
    __syncthreads();
    if (threadIdx.x == 0) {
        double s = (double)red[0] + (double)red[1] + (double)red[2] + (double)red[3];
        double sq = (double)red[4] + (double)red[5] + (double)red[6] + (double)red[7];
        atomicAdd(&stats[0], s);
        atomicAdd(&stats[1], sq);
    }
}

// ---------------- LayerNorm apply (f16 in, f16 out; stats finalize per block) ----------------
__global__ __launch_bounds__(256) void ln_apply(
    const uint2* __restrict__ in, __half* __restrict__ out,
    const float4* __restrict__ w4, const float4* __restrict__ b4,
    const double* __restrict__ stats, double cnt, int total4)
{
    int i = blockIdx.x * 256 + threadIdx.x;
    if (i >= total4) return;
    double mu = stats[0] / cnt;
    double var = stats[1] / cnt - mu * mu;
    if (var < 0.0) var = 0.0;
    float mean = (float)mu;
    float inv = (float)(1.0 / (sqrt(var) + (double)EPSLN));
    int c = i & 63;
    float4 xv = h4_to_f4(in[i]);
    float4 w = w4[c], b = b4[c];
    float4 o;
    o.x = fmaf((xv.x - mean) * inv, w.x, b.x);
    o.y = fmaf((xv.y - mean) * inv, w.y, b.y);
    o.z = fmaf((xv.z - mean) * inv, w.z, b.z);
    o.w = fmaf((xv.w - mean) * inv, w.w, b.w);
    o.x = o.x > 0.f ? o.x : expm1f(o.x);
    o.y = o.y > 0.f ? o.y : expm1f(o.y);
    o.z = o.z > 0.f ? o.z : expm1f(o.z);
    o.w = o.w > 0.f ? o.w : expm1f(o.w);
    store4(out + (size_t)i * 4, o);
}

// ---------------- driver ----------------
extern "C" void kernel_launch(void* const* d_in, const int* in_sizes, int n_in,
                              void* d_out, int out_size, void* d_ws, size_t ws_size,
                              hipStream_t stream)
{
    const float* x      = (const float*)d_in[0];
    const int*   ei     = (const int*)d_in[1];
    const float* eattr  = (const float*)d_in[2];
    const float* Wq1 = (const float*)d_in[3];  const float* bq1 = (const float*)d_in[4];
    const float* Wk1 = (const float*)d_in[5];  const float* bk1 = (const float*)d_in[6];
    const float* Wv1 = (const float*)d_in[7];  const float* bv1 = (const float*)d_in[8];
    const float* We1 = (const float*)d_in[9];
    const float* Ws1 = (const float*)d_in[10]; const float* bs1 = (const float*)d_in[11];
    const float* lnw1 = (const float*)d_in[12]; const float* lnb1 = (const float*)d_in[13];
    const float* Wq2 = (const float*)d_in[14]; const float* bq2 = (const float*)d_in[15];
    const float* Wk2 = (const float*)d_in[16]; const float* bk2 = (const float*)d_in[17];
    const float* Wv2 = (const float*)d_in[18]; const float* bv2 = (const float*)d_in[19];
    const float* We2 = (const float*)d_in[20];
    const float* Ws2 = (const float*)d_in[21]; const float* bs2 = (const float*)d_in[22];
    const float* lnw2 = (const float*)d_in[23]; const float* lnb2 = (const float*)d_in[24];
    const float* Wo  = (const float*)d_in[25]; const float* bo  = (const float*)d_in[26];

    const int N = in_sizes[0] / IN_DIM;
    const int E = in_sizes[2];
    const int* esrc = ei;
    const int* edst = ei + E;

    char* ws = (char*)d_ws;
    size_t off = 0;
    auto alloc = [&](size_t bytes) -> char* {
        char* p = ws + off;
        off += (bytes + 255) / 256 * 256;
        return p;
    };
    int*    counts = (int*)alloc((size_t)N * 4);
    int*    cursor = (int*)alloc((size_t)N * 4);
    double* stats  = (double*)alloc(64);
    size_t zbytes = off;
    int*    offs   = (int*)alloc((size_t)(N + 1) * 4);
    int2*   edat   = (int2*)alloc((size_t)E * 8);
    __half* xh     = (__half*)alloc((size_t)N * IN_DIM * 2);
    __half* qkvs   = (__half*)alloc((size_t)N * 1024 * 2);
    unsigned char* kv8 = (unsigned char*)alloc((size_t)N * 512);
    __half* hwork  = (__half*)alloc((size_t)N * HD * 2);
    __half* hio    = (__half*)alloc((size_t)N * HD * 2);
    __half* Wc1    = (__half*)alloc((size_t)1024 * IN_DIM * 2);
    __half* Wc2    = (__half*)alloc((size_t)1024 * HD * 2);
    __half* Wot    = (__half*)alloc((size_t)64 * HD * 2);
    float*  bc1    = (float*)alloc(1024 * 4);
    float*  bc2    = (float*)alloc(1024 * 4);

    hipMemsetAsync(d_ws, 0, zbytes, stream);

    int total4x = N * (IN_DIM / 4);
    int prepWork = total4x > E ? total4x : E;
    if (prepWork < 411648) prepWork = 411648;
    prep_k<<<(prepWork + 255) / 256, 256, 0, stream>>>(
        (const float4*)x, xh, total4x, edst, counts, E,
        Wq1, Wk1, Wv1, Ws1, Wq2, Wk2, Wv2, Ws2, Wo,
        bq1, bk1, bv1, bs1, bq2, bk2, bv2, bs2,
        Wc1, Wc2, Wot, bc1, bc2);

    scan_k<<<1, 1024, 0, stream>>>(counts, offs, N);
    scatter_k<<<(E + 255) / 256, 256, 0, stream>>>(esrc, edst, eattr, offs, cursor,
                                                   edat, E);

    dim3 gqkvs((N + BM - 1) / BM, 1024 / BN);
    dim3 gout((N + BM - 1) / BM, 1);
    int nGroups = (N + 3) / 4;
    int gaBlocks = nGroups < 2048 ? nGroups : 2048;
    int total4 = N * (HD / 4);
    dim3 gl((total4 + 255) / 256);

    // ---- layer 1 ----
    gemm_mfma<__half><<<gqkvs, 256, 0, stream>>>(xh, Wc1, bc1, qkvs, kv8, N, IN_DIM, 1024);
    attn_k<<<gaBlocks, 256, 0, stream>>>((const uint2*)qkvs, (const uint2*)kv8, We1,
                                         hwork, edat, offs, stats, N, nGroups);
    ln_apply<<<gl, 256, 0, stream>>>((const uint2*)hwork, hio,
                                     (const float4*)lnw1, (const float4*)lnb1,
                                     stats, (double)N * HD, total4);

    // ---- layer 2 ----
    gemm_mfma<__half><<<gqkvs, 256, 0, stream>>>(hio, Wc2, bc2, qkvs, kv8, N, HD, 1024);
    attn_k<<<gaBlocks, 256, 0, stream>>>((const uint2*)qkvs, (const uint2*)kv8, We2,
                                         hwork, edat, offs, stats + 2, N, nGroups);
    ln_apply<<<gl, 256, 0, stream>>>((const uint2*)hwork, hio,
                                     (const float4*)lnw2, (const float4*)lnb2,
                                     stats + 2, (double)N * HD, total4);

    // ---- output projection (fp32 out) ----
    gemm_mfma<float><<<gout, 256, 0, stream>>>(hio, Wot, bo, (float*)d_out, nullptr, N, HD, 64);
}

// Round 10
// 649.478 us; speedup vs baseline: 2.6935x; 1.0224x over previous
//
#include <hip/hip_runtime.h>
#include <hip/hip_fp16.h>
#include <math.h>

#define IN_DIM 128
#define HD 256
#define EPSLN 1e-5f

typedef _Float16 half8 __attribute__((ext_vector_type(8)));
typedef float f32x4 __attribute__((ext_vector_type(4)));
typedef float f32x2 __attribute__((ext_vector_type(2)));

// ---------------- helpers ----------------
__device__ inline void store4(float* p, float4 o) { *(float4*)p = o; }
__device__ inline void store4(__half* p, float4 o) {
    union { uint2 u; __half2 h[2]; } s;
    s.h[0] = __floats2half2_rn(o.x, o.y);
    s.h[1] = __floats2half2_rn(o.z, o.w);
    *(uint2*)p = s.u;
}
__device__ inline float4 h4_to_f4(uint2 u) {
    union { unsigned int w; __half2 h; } a, b;
    a.w = u.x; b.w = u.y;
    float2 lo = __half22float2(a.h), hi = __half22float2(b.h);
    return make_float4(lo.x, lo.y, hi.x, hi.y);
}
// 4 floats -> 4 packed fp8 e4m3 (OCP, gfx950 HW cvt)
__device__ inline unsigned int f4_to_fp8x4(float a, float b, float c, float d) {
    int v = 0;
    v = __builtin_amdgcn_cvt_pk_fp8_f32(a, b, v, false);
    v = __builtin_amdgcn_cvt_pk_fp8_f32(c, d, v, true);
    return (unsigned int)v;
}
__device__ inline float4 fp8x4_to_f4(unsigned int u) {
    f32x2 lo = __builtin_amdgcn_cvt_pk_f32_fp8((int)u, false);
    f32x2 hi = __builtin_amdgcn_cvt_pk_f32_fp8((int)u, true);
    return make_float4(lo.x, lo.y, hi.x, hi.y);
}

__device__ inline void async_copy16(const __half* g, _Float16* l) {
    __builtin_amdgcn_global_load_lds(
        (const __attribute__((address_space(1))) void*)g,
        (__attribute__((address_space(3))) void*)l,
        16, 0, 0);
}

// Packed output column mapping: q[0:256) | kv-interleaved[256:768) | skip[768:1024)
__device__ inline void unpermute_col(int n, int& sel, int& c) {
    if (n < 256) { sel = 0; c = n; }
    else if (n < 768) {
        int j = n - 256, chunk = j >> 3, w = j & 7;
        if (w < 4) { sel = 1; c = chunk * 4 + w; }
        else       { sel = 2; c = chunk * 4 + w - 4; }
    } else { sel = 3; c = n - 768; }
}

// ---------------- fused prep: pack x -> f16, pack weights/biases, count degrees ----
__global__ void prep_k(
    const float4* __restrict__ x, __half* __restrict__ xh, int total4,
    const int* __restrict__ dst, int* __restrict__ counts, int E,
    const float* __restrict__ Wq1, const float* __restrict__ Wk1,
    const float* __restrict__ Wv1, const float* __restrict__ Ws1,
    const float* __restrict__ Wq2, const float* __restrict__ Wk2,
    const float* __restrict__ Wv2, const float* __restrict__ Ws2,
    const float* __restrict__ Wo,
    const float* __restrict__ bq1, const float* __restrict__ bk1,
    const float* __restrict__ bv1, const float* __restrict__ bs1,
    const float* __restrict__ bq2, const float* __restrict__ bk2,
    const float* __restrict__ bv2, const float* __restrict__ bs2,
    __half* __restrict__ Wc1, __half* __restrict__ Wc2, __half* __restrict__ Wot,
    float* __restrict__ bc1, float* __restrict__ bc2)
{
    int idx = blockIdx.x * 256 + threadIdx.x;
    if (idx < total4) store4(xh + (size_t)idx * 4, x[idx]);
    if (idx < E) atomicAdd(&counts[dst[idx]], 1);
    if (idx < 131072) {
        int n = idx >> 7, k = idx & 127;
        int sel, c; unpermute_col(n, sel, c);
        const float* W = (sel == 0) ? Wq1 : (sel == 1) ? Wk1 : (sel == 2) ? Wv1 : Ws1;
        Wc1[idx] = __float2half(W[(size_t)k * 256 + c]);
    } else if (idx < 393216) {
        int j = idx - 131072;
        int n = j >> 8, k = j & 255;
        int sel, c; unpermute_col(n, sel, c);
        const float* W = (sel == 0) ? Wq2 : (sel == 1) ? Wk2 : (sel == 2) ? Wv2 : Ws2;
        Wc2[j] = __float2half(W[(size_t)k * 256 + c]);
    } else if (idx < 409600) {
        int j = idx - 393216;
        int n = j >> 8, k = j & 255;
        Wot[j] = __float2half(Wo[(size_t)k * 64 + n]);
    } else if (idx < 410624) {
        int n = idx - 409600;
        int sel, c; unpermute_col(n, sel, c);
        const float* b = (sel == 0) ? bq1 : (sel == 1) ? bk1 : (sel == 2) ? bv1 : bs1;
        bc1[n] = b[c];
    } else if (idx < 411648) {
        int n = idx - 410624;
        int sel, c; unpermute_col(n, sel, c);
        const float* b = (sel == 0) ? bq2 : (sel == 1) ? bk2 : (sel == 2) ? bv2 : bs2;
        bc2[n] = b[c];
    }
}

// ---------------- MFMA GEMM: C[M x Nc] = A[M x K] @ Wt^T + bias ----------------
#define BM 128
#define BN 128
#define BK 64
#define TROWB 272   // f16 out-tile row stride (bytes)

template <typename OT>
__global__ __launch_bounds__(256) void gemm_mfma(
    const __half* __restrict__ A, const __half* __restrict__ Wt,
    const float* __restrict__ bias, OT* __restrict__ C,
    unsigned char* __restrict__ kv8,
    int M, int K, int Nc)
{
    __shared__ char smem[BM * TROWB];
    _Float16* As = (_Float16*)smem;
    _Float16* Bs = (_Float16*)(smem + 16384);

    int tid = threadIdx.x;
    int lane = tid & 63, w = tid >> 6;
    int wm = w >> 1, wn = w & 1;
    int quad = lane >> 4, l16 = lane & 15;
    int row0 = blockIdx.x * BM, col0 = blockIdx.y * BN;

    f32x4 acc[4][4];
#pragma unroll
    for (int i = 0; i < 4; i++)
#pragma unroll
        for (int j = 0; j < 4; j++) acc[i][j] = (f32x4){0.f, 0.f, 0.f, 0.f};

    int srow = lane >> 3;
    int schunk = lane & 7;

    for (int k0 = 0; k0 < K; k0 += BK) {
#pragma unroll
        for (int t = 0; t < 4; t++) {
            int r = w * 32 + t * 8 + srow;
            int gr = row0 + r; if (gr > M - 1) gr = M - 1;
            int gchunk = schunk ^ (r & 7);
            async_copy16(&A[(size_t)gr * K + k0 + gchunk * 8], &As[(w * 32 + t * 8) * 64]);
        }
#pragma unroll
        for (int t = 0; t < 4; t++) {
            int r = w * 32 + t * 8 + srow;
            int gc = col0 + r; if (gc > Nc - 1) gc = Nc - 1;
            int gchunk = schunk ^ (r & 7);
            async_copy16(&Wt[(size_t)gc * K + k0 + gchunk * 8], &Bs[(w * 32 + t * 8) * 64]);
        }
        __syncthreads();

#pragma unroll
        for (int ks = 0; ks < 2; ks++) {
            half8 af[4], bf[4];
#pragma unroll
            for (int i = 0; i < 4; i++) {
                int ra = wm * 64 + i * 16 + l16;
                af[i] = *(half8*)&As[ra * 64 + (((ks * 4 + quad) ^ (ra & 7)) * 8)];
                int rb = wn * 64 + i * 16 + l16;
                bf[i] = *(half8*)&Bs[rb * 64 + (((ks * 4 + quad) ^ (rb & 7)) * 8)];
            }
#pragma unroll
            for (int i = 0; i < 4; i++)
#pragma unroll
                for (int j = 0; j < 4; j++)
                    acc[i][j] = __builtin_amdgcn_mfma_f32_16x16x32_f16(af[i], bf[j], acc[i][j], 0, 0, 0);
        }
        __syncthreads();
    }

    if constexpr (sizeof(OT) == 2) {
#pragma unroll
        for (int j = 0; j < 4; j++) {
            int tcol = wn * 64 + j * 16 + l16;
            float bb = (col0 + tcol < Nc) ? bias[col0 + tcol] : 0.f;
#pragma unroll
            for (int i = 0; i < 4; i++) {
#pragma unroll
                for (int r = 0; r < 4; r++) {
                    int trow = wm * 64 + i * 16 + quad * 4 + r;
                    ((__half*)(smem + trow * TROWB))[tcol] = __float2half(acc[i][j][r] + bb);
                }
            }
        }
        __syncthreads();
        bool iskv = (col0 >= 256) && (col0 < 768);
        int crow = tid >> 4, cchunk = tid & 15;
        for (int p = 0; p < 8; p++) {
            int trow = p * 16 + crow;
            int grow = row0 + trow;
            if (grow >= M) continue;
            uint4 val = *(uint4*)(smem + trow * TROWB + cchunk * 16);
            if (iskv) {
                float4 lo = h4_to_f4(make_uint2(val.x, val.y));
                float4 hi = h4_to_f4(make_uint2(val.z, val.w));
                uint2 o8;
                o8.x = f4_to_fp8x4(lo.x, lo.y, lo.z, lo.w);
                o8.y = f4_to_fp8x4(hi.x, hi.y, hi.z, hi.w);
                *(uint2*)&kv8[(size_t)grow * 512 + (col0 - 256) + cchunk * 8] = o8;
            } else {
                *(uint4*)&((__half*)C)[(size_t)grow * Nc + col0 + cchunk * 8] = val;
            }
        }
    } else {
#pragma unroll
        for (int i = 0; i < 4; i++) {
#pragma unroll
            for (int j = 0; j < 4; j++) {
                int gcol = col0 + wn * 64 + j * 16 + l16;
                if (gcol >= Nc) continue;
                float bb = bias[gcol];
#pragma unroll
                for (int r = 0; r < 4; r++) {
                    int grow = row0 + wm * 64 + i * 16 + quad * 4 + r;
                    if (grow < M) ((float*)C)[(size_t)grow * Nc + gcol] = acc[i][j][r] + bb;
                }
            }
        }
    }
}

// ---------------- edge bucketing ----------------
__global__ __launch_bounds__(1024) void scan_k(const int* __restrict__ counts,
                                               int* __restrict__ offs, int n)
{
    __shared__ int wsum[16];
    __shared__ int wpre[16];
    int tid = threadIdx.x, lane = tid & 63, wid = tid >> 6;
    int per = (n + 1023) / 1024;
    int start = tid * per, end = min(start + per, n);
    int sum = 0;
    for (int i = start; i < end; i++) sum += counts[i];
    int v = sum;
#pragma unroll
    for (int d = 1; d < 64; d <<= 1) {
        int t = __shfl_up(v, (unsigned)d, 64);
        if (lane >= d) v += t;
    }
    if (lane == 63) wsum[wid] = v;
    __syncthreads();
    if (tid == 0) {
        int acc = 0;
        for (int i = 0; i < 16; i++) { wpre[i] = acc; acc += wsum[i]; }
    }
    __syncthreads();
    int pre = wpre[wid] + v - sum;
    for (int i = start; i < end; i++) { offs[i] = pre; pre += counts[i]; }
    if (end == n && start <= n) offs[n] = pre;
}

__global__ void scatter_k(const int* __restrict__ src, const int* __restrict__ dst,
                          const float* __restrict__ attr, const int* __restrict__ offs,
                          int* __restrict__ cursor, int2* __restrict__ edat, int E)
{
    int e = blockIdx.x * 256 + threadIdx.x;
    if (e < E) {
        int d = dst[e];
        int p = offs[d] + atomicAdd(&cursor[d], 1);
        edat[p] = make_int2(src[e], __float_as_int(attr[e]));
    }
}

// ---------------- attention: one wave per dst node, batched online softmax ----------------
// q/skip from qkvs f16; k,v from kv8 (fp8 e4m3, k4|v4 per 8B chunk).
// Two-phase batches of 8: scores -> one batch-max rescale -> weighted accumulate.
// Ping-pong prefetch of the next batch overlaps gathers with compute.
__global__ __launch_bounds__(256) void attn_k(
    const uint2* __restrict__ q2, const uint2* __restrict__ kv8u2,
    const float* __restrict__ We,
    __half* __restrict__ hwork, const int2* __restrict__ edat,
    const int* __restrict__ offs,
    double* __restrict__ stats, int n, int nGroups)
{
    int lane = threadIdx.x & 63;
    int wid = threadIdx.x >> 6;
    float4 we = ((const float4*)We)[lane];
    float tsum = 0.f, tsq = 0.f;

    for (int g = blockIdx.x; g < nGroups; g += gridDim.x) {
        int node = g * 4 + wid;
        if (node >= n) continue;
        float4 qv = h4_to_f4(q2[(size_t)node * 256 + lane]);
        float qwe = qv.x * we.x + qv.y * we.y + qv.z * we.z + qv.w * we.w;
        qwe += __shfl_xor(qwe, 1);
        qwe += __shfl_xor(qwe, 2);
        qwe += __shfl_xor(qwe, 4);

        float4 accv = make_float4(0.f, 0.f, 0.f, 0.f);
        float sat = 0.f;
        float m = -INFINITY, l = 0.f;
        int i0 = offs[node], i1 = offs[node + 1];
        int rem = i1 - i0;

        int2 edA[8], edB[8];
        uint2 kvA[8], kvB[8];

        auto loadB = [&](int p, int c, int2* ed, uint2* kv) {
#pragma unroll
            for (int u = 0; u < 8; u++) {
                int uu = u < c ? u : c - 1;
                ed[u] = edat[p + uu];
            }
#pragma unroll
            for (int u = 0; u < 8; u++)
                kv[u] = kv8u2[(size_t)ed[u].x * 64 + lane];
        };

        auto procB = [&](const int2* ed, const uint2* kv, int c) {
            float p8[8];
#pragma unroll
            for (int u = 0; u < 8; u++) {
                float4 kk = fp8x4_to_f4(kv[u].x);
                float p = qv.x * kk.x + qv.y * kk.y + qv.z * kk.z + qv.w * kk.w;
                p += __shfl_xor(p, 1);
                p += __shfl_xor(p, 2);
                p += __shfl_xor(p, 4);
                p8[u] = fmaf(__int_as_float(ed[u].y), qwe, p) * 0.17677669529663687f;
            }
            float mx = -INFINITY;
#pragma unroll
            for (int u = 0; u < 8; u++)
                if (u < c) mx = fmaxf(mx, p8[u]);
            float mn = fmaxf(m, mx);
            float corr = __expf(m - mn);   // 0 on first batch (m=-inf)
            l *= corr; sat *= corr;
            accv.x *= corr; accv.y *= corr; accv.z *= corr; accv.w *= corr;
#pragma unroll
            for (int u = 0; u < 8; u++) {
                if (u >= c) continue;
                float wgt = __expf(p8[u] - mn);
                l += wgt;
                sat = fmaf(wgt, __int_as_float(ed[u].y), sat);
                float4 vv = fp8x4_to_f4(kv[u].y);
                accv.x = fmaf(wgt, vv.x, accv.x);
                accv.y = fmaf(wgt, vv.y, accv.y);
                accv.z = fmaf(wgt, vv.z, accv.z);
                accv.w = fmaf(wgt, vv.w, accv.w);
            }
            m = mn;
        };

        int nb = (rem + 7) >> 3;
        if (nb > 0) {
            int lastc = rem - (nb - 1) * 8;     // 1..8
            loadB(i0, (nb == 1) ? lastc : 8, edA, kvA);
            int b = 0;
            while (true) {
                // A holds batch b
                if (b + 1 < nb) loadB(i0 + (b + 1) * 8, (b + 1 == nb - 1) ? lastc : 8, edB, kvB);
                procB(edA, kvA, (b == nb - 1) ? lastc : 8);
                b++;
                if (b >= nb) break;
                // B holds batch b
                if (b + 1 < nb) loadB(i0 + (b + 1) * 8, (b + 1 == nb - 1) ? lastc : 8, edA, kvA);
                procB(edB, kvB, (b == nb - 1) ? lastc : 8);
                b++;
                if (b >= nb) break;
            }
        }

        float inv = (l > 0.f) ? 1.f / l : 0.f;
        float4 sk = h4_to_f4(q2[(size_t)node * 256 + 192 + lane]);
        float sw = sat * inv;
        float4 o;
        o.x = fmaf(accv.x, inv, fmaf(sw, we.x, sk.x));
        o.y = fmaf(accv.y, inv, fmaf(sw, we.y, sk.y));
        o.z = fmaf(accv.z, inv, fmaf(sw, we.z, sk.z));
        o.w = fmaf(accv.w, inv, fmaf(sw, we.w, sk.w));
        store4(hwork + (size_t)node * 256 + lane * 4, o);
        tsum += o.x + o.y + o.z + o.w;
        tsq += o.x * o.x + o.y * o.y + o.z * o.z + o.w * o.w;
    }

#pragma unroll
    for (int d = 1; d < 64; d <<= 1) {
        tsum += __shfl_xor(tsum, d);
        tsq += __shfl_xor(tsq, d);
    }
    __shared__ float red[8];
    if (lane == 0) { red[wid] = tsum; red[4 + wid] = tsq; }
    __syncthreads();
    if (threadIdx.x == 0) {
        double s = (double)red[0] + (double)red[1] + (double)red[2] + (double)red[3];
        double sq = (double)red[4] + (double)red[5] + (double)red[6] + (double)red[7];
        atomicAdd(&stats[0], s);
        atomicAdd(&stats[1], sq);
    }
}

// ---------------- LayerNorm apply (f16 in, f16 out; stats finalize per block) ----------------
__global__ __launch_bounds__(256) void ln_apply(
    const uint2* __restrict__ in, __half* __restrict__ out,
    const float4* __restrict__ w4, const float4* __restrict__ b4,
    const double* __restrict__ stats, double cnt, int total4)
{
    int i = blockIdx.x * 256 + threadIdx.x;
    if (i >= total4) return;
    double mu = stats[0] / cnt;
    double var = stats[1] / cnt - mu * mu;
    if (var < 0.0) var = 0.0;
    float mean = (float)mu;
    float inv = (float)(1.0 / (sqrt(var) + (double)EPSLN));
    int c = i & 63;
    float4 xv = h4_to_f4(in[i]);
    float4 w = w4[c], b = b4[c];
    float4 o;
    o.x = fmaf((xv.x - mean) * inv, w.x, b.x);
    o.y = fmaf((xv.y - mean) * inv, w.y, b.y);
    o.z = fmaf((xv.z - mean) * inv, w.z, b.z);
    o.w = fmaf((xv.w - mean) * inv, w.w, b.w);
    o.x = o.x > 0.f ? o.x : expm1f(o.x);
    o.y = o.y > 0.f ? o.y : expm1f(o.y);
    o.z = o.z > 0.f ? o.z : expm1f(o.z);
    o.w = o.w > 0.f ? o.w : expm1f(o.w);
    store4(out + (size_t)i * 4, o);
}

// ---------------- driver ----------------
extern "C" void kernel_launch(void* const* d_in, const int* in_sizes, int n_in,
                              void* d_out, int out_size, void* d_ws, size_t ws_size,
                              hipStream_t stream)
{
    const float* x      = (const float*)d_in[0];
    const int*   ei     = (const int*)d_in[1];
    const float* eattr  = (const float*)d_in[2];
    const float* Wq1 = (const float*)d_in[3];  const float* bq1 = (const float*)d_in[4];
    const float* Wk1 = (const float*)d_in[5];  const float* bk1 = (const float*)d_in[6];
    const float* Wv1 = (const float*)d_in[7];  const float* bv1 = (const float*)d_in[8];
    const float* We1 = (const float*)d_in[9];
    const float* Ws1 = (const float*)d_in[10]; const float* bs1 = (const float*)d_in[11];
    const float* lnw1 = (const float*)d_in[12]; const float* lnb1 = (const float*)d_in[13];
    const float* Wq2 = (const float*)d_in[14]; const float* bq2 = (const float*)d_in[15];
    const float* Wk2 = (const float*)d_in[16]; const float* bk2 = (const float*)d_in[17];
    const float* Wv2 = (const float*)d_in[18]; const float* bv2 = (const float*)d_in[19];
    const float* We2 = (const float*)d_in[20];
    const float* Ws2 = (const float*)d_in[21]; const float* bs2 = (const float*)d_in[22];
    const float* lnw2 = (const float*)d_in[23]; const float* lnb2 = (const float*)d_in[24];
    const float* Wo  = (const float*)d_in[25]; const float* bo  = (const float*)d_in[26];

    const int N = in_sizes[0] / IN_DIM;
    const int E = in_sizes[2];
    const int* esrc = ei;
    const int* edst = ei + E;

    char* ws = (char*)d_ws;
    size_t off = 0;
    auto alloc = [&](size_t bytes) -> char* {
        char* p = ws + off;
        off += (bytes + 255) / 256 * 256;
        return p;
    };
    int*    counts = (int*)alloc((size_t)N * 4);
    int*    cursor = (int*)alloc((size_t)N * 4);
    double* stats  = (double*)alloc(64);
    size_t zbytes = off;
    int*    offs   = (int*)alloc((size_t)(N + 1) * 4);
    int2*   edat   = (int2*)alloc((size_t)E * 8);
    __half* xh     = (__half*)alloc((size_t)N * IN_DIM * 2);
    __half* qkvs   = (__half*)alloc((size_t)N * 1024 * 2);
    unsigned char* kv8 = (unsigned char*)alloc((size_t)N * 512);
    __half* hwork  = (__half*)alloc((size_t)N * HD * 2);
    __half* hio    = (__half*)alloc((size_t)N * HD * 2);
    __half* Wc1    = (__half*)alloc((size_t)1024 * IN_DIM * 2);
    __half* Wc2    = (__half*)alloc((size_t)1024 * HD * 2);
    __half* Wot    = (__half*)alloc((size_t)64 * HD * 2);
    float*  bc1    = (float*)alloc(1024 * 4);
    float*  bc2    = (float*)alloc(1024 * 4);

    hipMemsetAsync(d_ws, 0, zbytes, stream);

    int total4x = N * (IN_DIM / 4);
    int prepWork = total4x > E ? total4x : E;
    if (prepWork < 411648) prepWork = 411648;
    prep_k<<<(prepWork + 255) / 256, 256, 0, stream>>>(
        (const float4*)x, xh, total4x, edst, counts, E,
        Wq1, Wk1, Wv1, Ws1, Wq2, Wk2, Wv2, Ws2, Wo,
        bq1, bk1, bv1, bs1, bq2, bk2, bv2, bs2,
        Wc1, Wc2, Wot, bc1, bc2);

    scan_k<<<1, 1024, 0, stream>>>(counts, offs, N);
    scatter_k<<<(E + 255) / 256, 256, 0, stream>>>(esrc, edst, eattr, offs, cursor,
                                                   edat, E);

    dim3 gqkvs((N + BM - 1) / BM, 1024 / BN);
    dim3 gout((N + BM - 1) / BM, 1);
    int nGroups = (N + 3) / 4;
    int gaBlocks = nGroups < 2048 ? nGroups : 2048;
    int total4 = N * (HD / 4);
    dim3 gl((total4 + 255) / 256);

    // ---- layer 1 ----
    gemm_mfma<__half><<<gqkvs, 256, 0, stream>>>(xh, Wc1, bc1, qkvs, kv8, N, IN_DIM, 1024);
    attn_k<<<gaBlocks, 256, 0, stream>>>((const uint2*)qkvs, (const uint2*)kv8, We1,
                                         hwork, edat, offs, stats, N, nGroups);
    ln_apply<<<gl, 256, 0, stream>>>((const uint2*)hwork, hio,
                                     (const float4*)lnw1, (const float4*)lnb1,
                                     stats, (double)N * HD, total4);

    // ---- layer 2 ----
    gemm_mfma<__half><<<gqkvs, 256, 0, stream>>>(hio, Wc2, bc2, qkvs, kv8, N, HD, 1024);
    attn_k<<<gaBlocks, 256, 0, stream>>>((const uint2*)qkvs, (const uint2*)kv8, We2,
                                         hwork, edat, offs, stats + 2, N, nGroups);
    ln_apply<<<gl, 256, 0, stream>>>((const uint2*)hwork, hio,
                                     (const float4*)lnw2, (const float4*)lnb2,
                                     stats + 2, (double)N * HD, total4);

    // ---- output projection (fp32 out) ----
    gemm_mfma<float><<<gout, 256, 0, stream>>>(hio, Wot, bo, (float*)d_out, nullptr, N, HD, 64);
}